// Round 1
// baseline (249.185 us; speedup 1.0000x reference)
//
#include <hip/hip_runtime.h>

// Problem constants (fixed by setup_inputs): B=32, T=256, D=512, P=20
#define BB 32
#define TT 256
#define DD 512
#define PP 20
#define EPSF 1e-12f
#define BTP (BB * TT * PP)   // 163840

// ---------------------------------------------------------------------------
// K1: per-row inverse L2 norms for inp_a and inp_b.  grid = B*T blocks, 64 thr
// ---------------------------------------------------------------------------
__global__ __launch_bounds__(64)
void k_rownorm_ab(const float* __restrict__ a, const float* __restrict__ b,
                  float* __restrict__ inv_a, float* __restrict__ inv_b) {
    const int row  = blockIdx.x;          // 0 .. B*T-1
    const int lane = threadIdx.x;         // 0 .. 63
    const float4* pa = (const float4*)(a + (size_t)row * DD);
    const float4* pb = (const float4*)(b + (size_t)row * DD);
    float sa = 0.f, sb = 0.f;
#pragma unroll
    for (int i = 0; i < 2; ++i) {
        float4 va = pa[i * 64 + lane];
        float4 vb = pb[i * 64 + lane];
        sa += va.x * va.x + va.y * va.y + va.z * va.z + va.w * va.w;
        sb += vb.x * vb.x + vb.y * vb.y + vb.z * vb.z + vb.w * vb.w;
    }
#pragma unroll
    for (int off = 32; off; off >>= 1) {
        sa += __shfl_down(sa, off);
        sb += __shfl_down(sb, off);
    }
    if (lane == 0) {
        inv_a[row] = rsqrtf(fmaxf(sa, EPSF));
        inv_b[row] = rsqrtf(fmaxf(sb, EPSF));
    }
}

// ---------------------------------------------------------------------------
// K3: per-row inverse L2 norm of alphaT (B*D rows of length D)
// ---------------------------------------------------------------------------
__global__ __launch_bounds__(64)
void k_rownorm_c(const float* __restrict__ x, float* __restrict__ inv) {
    const int row  = blockIdx.x;          // 0 .. B*D-1
    const int lane = threadIdx.x;
    const float4* px = (const float4*)(x + (size_t)row * DD);
    float s = 0.f;
#pragma unroll
    for (int i = 0; i < 2; ++i) {
        float4 v = px[i * 64 + lane];
        s += v.x * v.x + v.y * v.y + v.z * v.z + v.w * v.w;
    }
#pragma unroll
    for (int off = 32; off; off >>= 1) s += __shfl_down(s, off);
    if (lane == 0) inv[row] = rsqrtf(fmaxf(s, EPSF));
}

// ---------------------------------------------------------------------------
// K2: alphaT[b,e,d] = sum_t (a[b,t,e]*inv_a[b,t]) * (b[b,t,d]*inv_b[b,t])
// TN GEMM:  A = a (K=T x M=D, row-major), B = b (K=T x N=D), C = alphaT (M x N)
// Tile 64x64, BK=16, 256 threads, 4x4 per thread.
// ---------------------------------------------------------------------------
__global__ __launch_bounds__(256)
void k_gemm_tn(const float* __restrict__ A, const float* __restrict__ Bm,
               const float* __restrict__ invA, const float* __restrict__ invB,
               float* __restrict__ C) {
    const int bz = blockIdx.z;
    const int m0 = blockIdx.y * 64;
    const int n0 = blockIdx.x * 64;
    const float* Ab = A + (size_t)bz * TT * DD;
    const float* Bb = Bm + (size_t)bz * TT * DD;
    const float* ia = invA + bz * TT;
    const float* ib = invB + bz * TT;
    float* Cb = C + (size_t)bz * DD * DD;

    __shared__ float As[16][68];
    __shared__ float Bs[16][68];

    const int tid = threadIdx.x;
    const int tx = tid & 15, ty = tid >> 4;
    const int lk = tid >> 4;             // k-row within tile, 0..15
    const int lm = (tid & 15) * 4;       // col within tile, 0..60

    float acc[4][4] = {};

    for (int k0 = 0; k0 < TT; k0 += 16) {
        const float sa = ia[k0 + lk];
        const float sb = ib[k0 + lk];
        float4 va = *(const float4*)(Ab + (size_t)(k0 + lk) * DD + m0 + lm);
        float4 vb = *(const float4*)(Bb + (size_t)(k0 + lk) * DD + n0 + lm);
        va.x *= sa; va.y *= sa; va.z *= sa; va.w *= sa;
        vb.x *= sb; vb.y *= sb; vb.z *= sb; vb.w *= sb;
        *(float4*)&As[lk][lm] = va;
        *(float4*)&Bs[lk][lm] = vb;
        __syncthreads();
#pragma unroll
        for (int k = 0; k < 16; ++k) {
            float4 a4 = *(const float4*)&As[k][ty * 4];
            float4 b4 = *(const float4*)&Bs[k][tx * 4];
            const float av[4] = {a4.x, a4.y, a4.z, a4.w};
            const float bv[4] = {b4.x, b4.y, b4.z, b4.w};
#pragma unroll
            for (int i = 0; i < 4; ++i)
#pragma unroll
                for (int j = 0; j < 4; ++j)
                    acc[i][j] = fmaf(av[i], bv[j], acc[i][j]);
        }
        __syncthreads();
    }
#pragma unroll
    for (int i = 0; i < 4; ++i) {
        float4 o = {acc[i][0], acc[i][1], acc[i][2], acc[i][3]};
        *(float4*)(Cb + (size_t)(m0 + ty * 4 + i) * DD + n0 + tx * 4) = o;
    }
}

// ---------------------------------------------------------------------------
// K4: hmean[b,t,e] = sum_d (b[b,t,d]*inv_b[b,t]) * (alphaT[b,e,d]*inv_c[b,e])
// NT GEMM: A = b (M=T x K=D), B = alphaT (N=D x K=D), C = hmean (M x N)
// Tiles transposed into LDS as [BK][64] so the inner loop matches k_gemm_tn.
// ---------------------------------------------------------------------------
__global__ __launch_bounds__(256)
void k_gemm_nt(const float* __restrict__ A, const float* __restrict__ Bm,
               const float* __restrict__ invA, const float* __restrict__ invB,
               float* __restrict__ C) {
    const int bz = blockIdx.z;
    const int m0 = blockIdx.y * 64;      // t
    const int n0 = blockIdx.x * 64;      // e
    const float* Ab = A + (size_t)bz * TT * DD;
    const float* Bb = Bm + (size_t)bz * DD * DD;
    const float* ia = invA + bz * TT;
    const float* ic = invB + bz * DD;
    float* Cb = C + (size_t)bz * TT * DD;

    __shared__ float As[16][68];
    __shared__ float Bs[16][68];

    const int tid = threadIdx.x;
    const int tx = tid & 15, ty = tid >> 4;
    const int lr = tid >> 2;             // row within tile, 0..63
    const int lc = (tid & 3) * 4;        // k-col within tile, 0..12

    const float sa = ia[m0 + lr];        // constant across k-loop
    const float sb = ic[n0 + lr];

    float acc[4][4] = {};

    for (int k0 = 0; k0 < DD; k0 += 16) {
        float4 va = *(const float4*)(Ab + (size_t)(m0 + lr) * DD + k0 + lc);
        float4 vb = *(const float4*)(Bb + (size_t)(n0 + lr) * DD + k0 + lc);
        va.x *= sa; va.y *= sa; va.z *= sa; va.w *= sa;
        vb.x *= sb; vb.y *= sb; vb.z *= sb; vb.w *= sb;
        As[lc + 0][lr] = va.x; As[lc + 1][lr] = va.y;
        As[lc + 2][lr] = va.z; As[lc + 3][lr] = va.w;
        Bs[lc + 0][lr] = vb.x; Bs[lc + 1][lr] = vb.y;
        Bs[lc + 2][lr] = vb.z; Bs[lc + 3][lr] = vb.w;
        __syncthreads();
#pragma unroll
        for (int k = 0; k < 16; ++k) {
            float4 a4 = *(const float4*)&As[k][ty * 4];
            float4 b4 = *(const float4*)&Bs[k][tx * 4];
            const float av[4] = {a4.x, a4.y, a4.z, a4.w};
            const float bv[4] = {b4.x, b4.y, b4.z, b4.w};
#pragma unroll
            for (int i = 0; i < 4; ++i)
#pragma unroll
                for (int j = 0; j < 4; ++j)
                    acc[i][j] = fmaf(av[i], bv[j], acc[i][j]);
        }
        __syncthreads();
    }
#pragma unroll
    for (int i = 0; i < 4; ++i) {
        float4 o = {acc[i][0], acc[i][1], acc[i][2], acc[i][3]};
        *(float4*)(Cb + (size_t)(m0 + ty * 4 + i) * DD + n0 + tx * 4) = o;
    }
}

// ---------------------------------------------------------------------------
// K5: persp[b,t,p] = (sum_d a*h*w^2) * rsqrt(max(sum a^2 w^2,eps))
//                                    * rsqrt(max(sum h^2 w^2,eps))
// One 64-thread block per (b,t); write both output copies.
// ---------------------------------------------------------------------------
__global__ __launch_bounds__(64)
void k_persp(const float* __restrict__ a, const float* __restrict__ h,
             const float* __restrict__ W, float* __restrict__ out) {
    const int row  = blockIdx.x;         // b*T + t
    const int lane = threadIdx.x;
    const float4* pa = (const float4*)(a + (size_t)row * DD);
    const float4* ph = (const float4*)(h + (size_t)row * DD);
    float4 a0 = pa[lane], a1 = pa[64 + lane];
    float4 h0 = ph[lane], h1 = ph[64 + lane];
    const float av[8] = {a0.x, a0.y, a0.z, a0.w, a1.x, a1.y, a1.z, a1.w};
    const float hv[8] = {h0.x, h0.y, h0.z, h0.w, h1.x, h1.y, h1.z, h1.w};
    float ah[8], aa[8], hh[8];
#pragma unroll
    for (int q = 0; q < 8; ++q) {
        ah[q] = av[q] * hv[q];
        aa[q] = av[q] * av[q];
        hh[q] = hv[q] * hv[q];
    }
    for (int p = 0; p < PP; ++p) {
        const float4* pw = (const float4*)(W + (size_t)p * DD);
        float4 w0 = pw[lane], w1 = pw[64 + lane];
        const float wv[8] = {w0.x, w0.y, w0.z, w0.w, w1.x, w1.y, w1.z, w1.w};
        float s1 = 0.f, s2 = 0.f, s3 = 0.f;
#pragma unroll
        for (int q = 0; q < 8; ++q) {
            const float ww = wv[q] * wv[q];
            s1 = fmaf(ah[q], ww, s1);
            s2 = fmaf(aa[q], ww, s2);
            s3 = fmaf(hh[q], ww, s3);
        }
#pragma unroll
        for (int off = 1; off < 64; off <<= 1) {
            s1 += __shfl_xor(s1, off);
            s2 += __shfl_xor(s2, off);
            s3 += __shfl_xor(s3, off);
        }
        if (lane == 0) {
            const float v = s1 * rsqrtf(fmaxf(s2, EPSF)) * rsqrtf(fmaxf(s3, EPSF));
            out[(size_t)row * PP + p] = v;
            out[(size_t)BTP + (size_t)row * PP + p] = v;
        }
    }
}

// ---------------------------------------------------------------------------
extern "C" void kernel_launch(void* const* d_in, const int* in_sizes, int n_in,
                              void* d_out, int out_size, void* d_ws, size_t ws_size,
                              hipStream_t stream) {
    (void)in_sizes; (void)n_in; (void)out_size; (void)ws_size;
    const float* a = (const float*)d_in[0];   // (B,T,D)
    const float* b = (const float*)d_in[1];   // (B,T,D)
    const float* W = (const float*)d_in[2];   // (P,D)
    float* out = (float*)d_out;               // 2 * B*T*P floats

    char* ws = (char*)d_ws;
    float* alphaT = (float*)ws;                                   // B*D*D floats  (33.5 MB)
    float* hmean  = (float*)(ws + (size_t)BB * DD * DD * 4);      // B*T*D floats  (16.8 MB)
    float* inv_a  = (float*)(ws + (size_t)BB * DD * DD * 4
                                + (size_t)BB * TT * DD * 4);      // B*T
    float* inv_b  = inv_a + BB * TT;                              // B*T
    float* inv_c  = inv_b + BB * TT;                              // B*D

    // 1. row norms of a, b
    k_rownorm_ab<<<BB * TT, 64, 0, stream>>>(a, b, inv_a, inv_b);
    // 2. alphaT = na^T @ nb  (per batch)
    dim3 g2(DD / 64, DD / 64, BB);
    k_gemm_tn<<<g2, 256, 0, stream>>>(a, b, inv_a, inv_b, alphaT);
    // 3. row norms of alphaT (== column norms of alpha over axis d)
    k_rownorm_c<<<BB * DD, 64, 0, stream>>>(alphaT, inv_c);
    // 4. hmean = nb @ alpha_normalized   (NT against alphaT rows)
    dim3 g4(DD / 64, TT / 64, BB);
    k_gemm_nt<<<g4, 256, 0, stream>>>(b, alphaT, inv_b, inv_c, hmean);
    // 5. perspective cosine outputs (two identical copies)
    k_persp<<<BB * TT, 64, 0, stream>>>(a, hmean, W, out);
}

// Round 2
// 162.584 us; speedup vs baseline: 1.5327x; 1.5327x over previous
//
#include <hip/hip_runtime.h>

// Problem constants: B=32, T=256, D=512, P=20
#define BB 32
#define TT 256
#define DD 512
#define PP 20
#define EPSF 1e-12f
#define BTP (BB * TT * PP)   // 163840

typedef __attribute__((ext_vector_type(8))) short short8;
typedef __attribute__((ext_vector_type(4))) float f32x4;

__device__ inline unsigned short f2bf(float f) {
    unsigned u = __float_as_uint(f);
    u += 0x7fffu + ((u >> 16) & 1u);          // round-to-nearest-even
    return (unsigned short)(u >> 16);
}
__device__ inline unsigned pack2(float lo, float hi) {
    return (unsigned)f2bf(lo) | ((unsigned)f2bf(hi) << 16);
}

// ---------------------------------------------------------------------------
// K1: per-row inverse L2 norms for inp_a and inp_b. grid = B*T, 64 thr
// ---------------------------------------------------------------------------
__global__ __launch_bounds__(64)
void k_rownorm_ab(const float* __restrict__ a, const float* __restrict__ b,
                  float* __restrict__ inv_a, float* __restrict__ inv_b) {
    const int row  = blockIdx.x;
    const int lane = threadIdx.x;
    const float4* pa = (const float4*)(a + (size_t)row * DD);
    const float4* pb = (const float4*)(b + (size_t)row * DD);
    float sa = 0.f, sb = 0.f;
#pragma unroll
    for (int i = 0; i < 2; ++i) {
        float4 va = pa[i * 64 + lane];
        float4 vb = pb[i * 64 + lane];
        sa += va.x * va.x + va.y * va.y + va.z * va.z + va.w * va.w;
        sb += vb.x * vb.x + vb.y * vb.y + vb.z * vb.z + vb.w * vb.w;
    }
#pragma unroll
    for (int off = 32; off; off >>= 1) {
        sa += __shfl_down(sa, off);
        sb += __shfl_down(sb, off);
    }
    if (lane == 0) {
        inv_a[row] = rsqrtf(fmaxf(sa, EPSF));
        inv_b[row] = rsqrtf(fmaxf(sb, EPSF));
    }
}

// ---------------------------------------------------------------------------
// K2: naT_bf[b][e][s] = bf16( a[b][s][e] * inv_a[b][s] )  (LDS transpose)
// grid: (D/64, T/64, B), 256 thr
// ---------------------------------------------------------------------------
__global__ __launch_bounds__(256)
void k_mk_naT(const float* __restrict__ a, const float* __restrict__ inv_a,
              unsigned short* __restrict__ naT) {
    const int bz = blockIdx.z;
    const int e0 = blockIdx.x * 64;
    const int s0 = blockIdx.y * 64;
    __shared__ float Ts[64][65];
    const int tid = threadIdx.x;
    const float* ab = a + (size_t)bz * TT * DD;
#pragma unroll
    for (int i = 0; i < 4; ++i) {
        const int sr = (tid >> 4) + i * 16;
        const int ec = (tid & 15) * 4;
        float4 v = *(const float4*)(ab + (size_t)(s0 + sr) * DD + e0 + ec);
        const float s = inv_a[bz * TT + s0 + sr];
        Ts[sr][ec + 0] = v.x * s; Ts[sr][ec + 1] = v.y * s;
        Ts[sr][ec + 2] = v.z * s; Ts[sr][ec + 3] = v.w * s;
    }
    __syncthreads();
    unsigned short* nb = naT + (size_t)bz * DD * TT;
#pragma unroll
    for (int i = 0; i < 2; ++i) {
        const int el = (tid >> 3) + i * 32;
        const int s8 = (tid & 7) * 8;
        uint4 o;
        o.x = pack2(Ts[s8 + 0][el], Ts[s8 + 1][el]);
        o.y = pack2(Ts[s8 + 2][el], Ts[s8 + 3][el]);
        o.z = pack2(Ts[s8 + 4][el], Ts[s8 + 5][el]);
        o.w = pack2(Ts[s8 + 6][el], Ts[s8 + 7][el]);
        *(uint4*)(nb + (size_t)(e0 + el) * TT + s0 + s8) = o;
    }
}

// ---------------------------------------------------------------------------
// K3: G_bf[b][t][s] = bf16( sum_d nb[t,d]*nb[s,d] ),  nb = b*inv_b
// MFMA bf16 16x16x32.  Block 64x64 tile, 4 waves (2x2 of 32x32), BK=32.
// grid: (T/64, T/64, B), 256 thr
// ---------------------------------------------------------------------------
__global__ __launch_bounds__(256)
void k_gemm_g(const float* __restrict__ bmat, const float* __restrict__ inv_b,
              unsigned short* __restrict__ G) {
    const int bz = blockIdx.z;
    const int t0 = blockIdx.y * 64;
    const int s0 = blockIdx.x * 64;
    __shared__ __align__(16) unsigned short As[64 * 40];
    __shared__ __align__(16) unsigned short Bs[64 * 40];

    const int tid  = threadIdx.x;
    const int wave = tid >> 6, lane = tid & 63;
    const int quad = lane >> 4, ln = lane & 15;
    const int wm = wave >> 1, wn = wave & 1;

    const float* bb = bmat + (size_t)bz * TT * DD;
    const float* ib = inv_b + bz * TT;

    const int lr = tid >> 3;          // 0..31
    const int lc = (tid & 7) * 4;     // 0..28

    f32x4 acc[2][2];
#pragma unroll
    for (int i = 0; i < 2; ++i)
#pragma unroll
        for (int j = 0; j < 2; ++j)
#pragma unroll
            for (int r = 0; r < 4; ++r) acc[i][j][r] = 0.f;

    for (int k0 = 0; k0 < DD; k0 += 32) {
#pragma unroll
        for (int h = 0; h < 2; ++h) {
            const int row = lr + 32 * h;
            const int rA = t0 + row, rB = s0 + row;
            float4 va = *(const float4*)(bb + (size_t)rA * DD + k0 + lc);
            float4 vb = *(const float4*)(bb + (size_t)rB * DD + k0 + lc);
            const float sa = ib[rA], sb = ib[rB];
            uint2 pa, pb;
            pa.x = pack2(va.x * sa, va.y * sa); pa.y = pack2(va.z * sa, va.w * sa);
            pb.x = pack2(vb.x * sb, vb.y * sb); pb.y = pack2(vb.z * sb, vb.w * sb);
            *(uint2*)&As[row * 40 + lc] = pa;
            *(uint2*)&Bs[row * 40 + lc] = pb;
        }
        __syncthreads();
        short8 af[2], bf[2];
        af[0] = *(const short8*)&As[(wm * 32 + ln) * 40 + quad * 8];
        af[1] = *(const short8*)&As[(wm * 32 + 16 + ln) * 40 + quad * 8];
        bf[0] = *(const short8*)&Bs[(wn * 32 + ln) * 40 + quad * 8];
        bf[1] = *(const short8*)&Bs[(wn * 32 + 16 + ln) * 40 + quad * 8];
#pragma unroll
        for (int i = 0; i < 2; ++i)
#pragma unroll
            for (int j = 0; j < 2; ++j)
                acc[i][j] = __builtin_amdgcn_mfma_f32_16x16x32_bf16(
                    af[i], bf[j], acc[i][j], 0, 0, 0);
        __syncthreads();
    }
    unsigned short* Gb = G + (size_t)bz * TT * TT;
#pragma unroll
    for (int i = 0; i < 2; ++i)
#pragma unroll
        for (int j = 0; j < 2; ++j) {
            const int col = s0 + wn * 32 + j * 16 + ln;
#pragma unroll
            for (int r = 0; r < 4; ++r) {
                const int row = t0 + wm * 32 + i * 16 + quad * 4 + r;
                Gb[(size_t)row * TT + col] = f2bf(acc[i][j][r]);
            }
        }
}

// ---------------------------------------------------------------------------
// K4: H[b][t][e] = sum_s G[t,s] * na[s,e]   (A=G_bf, B=naT_bf, both K-contig)
//     fused epilogue: q[b][e] += sum_t na[t,e]*H[t,e]   (atomics)
// grid: (D/64, T/64, B), 256 thr
// ---------------------------------------------------------------------------
__global__ __launch_bounds__(256)
void k_gemm_h(const unsigned short* __restrict__ G,
              const unsigned short* __restrict__ naT,
              const float* __restrict__ a, const float* __restrict__ inv_a,
              float* __restrict__ H, float* __restrict__ q) {
    const int bz = blockIdx.z;
    const int t0 = blockIdx.y * 64;
    const int e0 = blockIdx.x * 64;
    __shared__ __align__(16) unsigned short As[64 * 40];
    __shared__ __align__(16) unsigned short Bs[64 * 40];
    __shared__ float qsum[64];

    const int tid  = threadIdx.x;
    const int wave = tid >> 6, lane = tid & 63;
    const int quad = lane >> 4, ln = lane & 15;
    const int wm = wave >> 1, wn = wave & 1;

    const unsigned short* Gb = G + (size_t)bz * TT * TT;
    const unsigned short* Nb = naT + (size_t)bz * DD * TT;

    const int lr = tid >> 2;          // 0..63
    const int c8 = (tid & 3) * 8;     // 0..24

    f32x4 acc[2][2];
#pragma unroll
    for (int i = 0; i < 2; ++i)
#pragma unroll
        for (int j = 0; j < 2; ++j)
#pragma unroll
            for (int r = 0; r < 4; ++r) acc[i][j][r] = 0.f;

    for (int k0 = 0; k0 < TT; k0 += 32) {
        *(uint4*)&As[lr * 40 + c8] =
            *(const uint4*)(Gb + (size_t)(t0 + lr) * TT + k0 + c8);
        *(uint4*)&Bs[lr * 40 + c8] =
            *(const uint4*)(Nb + (size_t)(e0 + lr) * TT + k0 + c8);
        __syncthreads();
        short8 af[2], bf[2];
        af[0] = *(const short8*)&As[(wm * 32 + ln) * 40 + quad * 8];
        af[1] = *(const short8*)&As[(wm * 32 + 16 + ln) * 40 + quad * 8];
        bf[0] = *(const short8*)&Bs[(wn * 32 + ln) * 40 + quad * 8];
        bf[1] = *(const short8*)&Bs[(wn * 32 + 16 + ln) * 40 + quad * 8];
#pragma unroll
        for (int i = 0; i < 2; ++i)
#pragma unroll
            for (int j = 0; j < 2; ++j)
                acc[i][j] = __builtin_amdgcn_mfma_f32_16x16x32_bf16(
                    af[i], bf[j], acc[i][j], 0, 0, 0);
        __syncthreads();
    }

    if (tid < 64) qsum[tid] = 0.f;
    __syncthreads();

    const float* ab = a + (size_t)bz * TT * DD;
    const float* ia = inv_a + bz * TT;
    float* Hb = H + (size_t)bz * TT * DD;
#pragma unroll
    for (int j = 0; j < 2; ++j) {
        const int col = e0 + wn * 32 + j * 16 + ln;
        float qp = 0.f;
#pragma unroll
        for (int i = 0; i < 2; ++i) {
#pragma unroll
            for (int r = 0; r < 4; ++r) {
                const int row = t0 + wm * 32 + i * 16 + quad * 4 + r;
                const float hv = acc[i][j][r];
                Hb[(size_t)row * DD + col] = hv;
                qp = fmaf(ab[(size_t)row * DD + col] * ia[row], hv, qp);
            }
        }
        qp += __shfl_xor(qp, 16);
        qp += __shfl_xor(qp, 32);
        if (quad == 0) atomicAdd(&qsum[wn * 32 + j * 16 + ln], qp);
    }
    __syncthreads();
    if (tid < 64) atomicAdd(q + bz * DD + e0 + tid, qsum[tid]);
}

// ---------------------------------------------------------------------------
// K5: persp with on-the-fly hmean = H * rsqrt(max(q,eps))
// ---------------------------------------------------------------------------
__global__ __launch_bounds__(64)
void k_persp(const float* __restrict__ a, const float* __restrict__ H,
             const float* __restrict__ q, const float* __restrict__ W,
             float* __restrict__ out) {
    const int row  = blockIdx.x;        // b*T + t
    const int b    = row >> 8;
    const int lane = threadIdx.x;
    const float4* pa = (const float4*)(a + (size_t)row * DD);
    const float4* ph = (const float4*)(H + (size_t)row * DD);
    const float4* pq = (const float4*)(q + (size_t)b * DD);
    float4 a0 = pa[lane], a1 = pa[64 + lane];
    float4 h0 = ph[lane], h1 = ph[64 + lane];
    float4 q0 = pq[lane], q1 = pq[64 + lane];
    const float av[8] = {a0.x, a0.y, a0.z, a0.w, a1.x, a1.y, a1.z, a1.w};
    float hv[8] = {h0.x, h0.y, h0.z, h0.w, h1.x, h1.y, h1.z, h1.w};
    const float qv[8] = {q0.x, q0.y, q0.z, q0.w, q1.x, q1.y, q1.z, q1.w};
    float ah[8], aa[8], hh[8];
#pragma unroll
    for (int t = 0; t < 8; ++t) {
        hv[t] *= rsqrtf(fmaxf(qv[t], EPSF));
        ah[t] = av[t] * hv[t];
        aa[t] = av[t] * av[t];
        hh[t] = hv[t] * hv[t];
    }
    for (int p = 0; p < PP; ++p) {
        const float4* pw = (const float4*)(W + (size_t)p * DD);
        float4 w0 = pw[lane], w1 = pw[64 + lane];
        const float wv[8] = {w0.x, w0.y, w0.z, w0.w, w1.x, w1.y, w1.z, w1.w};
        float s1 = 0.f, s2 = 0.f, s3 = 0.f;
#pragma unroll
        for (int t = 0; t < 8; ++t) {
            const float ww = wv[t] * wv[t];
            s1 = fmaf(ah[t], ww, s1);
            s2 = fmaf(aa[t], ww, s2);
            s3 = fmaf(hh[t], ww, s3);
        }
#pragma unroll
        for (int off = 1; off < 64; off <<= 1) {
            s1 += __shfl_xor(s1, off);
            s2 += __shfl_xor(s2, off);
            s3 += __shfl_xor(s3, off);
        }
        if (lane == 0) {
            const float v = s1 * rsqrtf(fmaxf(s2, EPSF)) * rsqrtf(fmaxf(s3, EPSF));
            out[(size_t)row * PP + p] = v;
            out[(size_t)BTP + (size_t)row * PP + p] = v;
        }
    }
}

// ---------------------------------------------------------------------------
extern "C" void kernel_launch(void* const* d_in, const int* in_sizes, int n_in,
                              void* d_out, int out_size, void* d_ws, size_t ws_size,
                              hipStream_t stream) {
    (void)in_sizes; (void)n_in; (void)out_size; (void)ws_size;
    const float* a = (const float*)d_in[0];   // (B,T,D)
    const float* b = (const float*)d_in[1];   // (B,T,D)
    const float* W = (const float*)d_in[2];   // (P,D)
    float* out = (float*)d_out;

    char* ws = (char*)d_ws;
    unsigned short* G_bf = (unsigned short*)ws;                        // 32*256*256*2 = 4 MB
    unsigned short* naT  = (unsigned short*)(ws + (4u << 20));         // 32*512*256*2 = 8 MB
    float* H    = (float*)(ws + (12u << 20));                          // 32*256*512*4 = 16 MB
    float* q    = (float*)(ws + (28u << 20));                          // 32*512*4 = 64 KB
    float* inv_a = (float*)(ws + (28u << 20) + (64u << 10));           // 32 KB
    float* inv_b = inv_a + BB * TT;

    hipMemsetAsync(q, 0, (size_t)BB * DD * sizeof(float), stream);

    k_rownorm_ab<<<BB * TT, 64, 0, stream>>>(a, b, inv_a, inv_b);

    dim3 gT(DD / 64, TT / 64, BB);
    k_mk_naT<<<gT, 256, 0, stream>>>(a, inv_a, naT);

    dim3 gG(TT / 64, TT / 64, BB);
    k_gemm_g<<<gG, 256, 0, stream>>>(b, inv_b, G_bf);

    dim3 gH(DD / 64, TT / 64, BB);
    k_gemm_h<<<gH, 256, 0, stream>>>(G_bf, naT, a, inv_a, H, q);

    k_persp<<<BB * TT, 64, 0, stream>>>(a, H, q, W, out);
}

// Round 3
// 147.407 us; speedup vs baseline: 1.6905x; 1.1030x over previous
//
#include <hip/hip_runtime.h>

// Problem constants: B=32, T=256, D=512, P=20
#define BB 32
#define TT 256
#define DD 512
#define PP 20
#define EPSF 1e-12f
#define BTP (BB * TT * PP)   // 163840

typedef __attribute__((ext_vector_type(8))) short short8;
typedef __attribute__((ext_vector_type(4))) float f32x4;

__device__ inline unsigned short f2bf(float f) {
    unsigned u = __float_as_uint(f);
    u += 0x7fffu + ((u >> 16) & 1u);          // round-to-nearest-even
    return (unsigned short)(u >> 16);
}
__device__ inline unsigned pack2(float lo, float hi) {
    return (unsigned)f2bf(lo) | ((unsigned)f2bf(hi) << 16);
}
__device__ inline float bf2f(unsigned s) {    // s = 16-bit bf16 payload
    return __uint_as_float(s << 16);
}

// ---------------------------------------------------------------------------
// K1: per-row inverse L2 norms for a and b; also emit nb_bf = bf16(b*inv_b)
// row-major (K-contiguous for the G GEMM). grid = B*T, 64 thr.
// Lane l owns d = 8l .. 8l+7.
// ---------------------------------------------------------------------------
__global__ __launch_bounds__(64)
void k_prep(const float* __restrict__ a, const float* __restrict__ b,
            float* __restrict__ inv_a, float* __restrict__ inv_b,
            unsigned short* __restrict__ nb_bf) {
    const int row  = blockIdx.x;
    const int lane = threadIdx.x;
    const float4* pa = (const float4*)(a + (size_t)row * DD);
    const float4* pb = (const float4*)(b + (size_t)row * DD);
    float4 a0 = pa[2 * lane], a1 = pa[2 * lane + 1];
    float4 b0 = pb[2 * lane], b1 = pb[2 * lane + 1];
    float sa = a0.x * a0.x + a0.y * a0.y + a0.z * a0.z + a0.w * a0.w
             + a1.x * a1.x + a1.y * a1.y + a1.z * a1.z + a1.w * a1.w;
    float sb = b0.x * b0.x + b0.y * b0.y + b0.z * b0.z + b0.w * b0.w
             + b1.x * b1.x + b1.y * b1.y + b1.z * b1.z + b1.w * b1.w;
#pragma unroll
    for (int off = 1; off < 64; off <<= 1) {
        sa += __shfl_xor(sa, off);
        sb += __shfl_xor(sb, off);
    }
    const float ia_ = rsqrtf(fmaxf(sa, EPSF));
    const float ib_ = rsqrtf(fmaxf(sb, EPSF));
    if (lane == 0) { inv_a[row] = ia_; inv_b[row] = ib_; }
    uint4 o;
    o.x = pack2(b0.x * ib_, b0.y * ib_);
    o.y = pack2(b0.z * ib_, b0.w * ib_);
    o.z = pack2(b1.x * ib_, b1.y * ib_);
    o.w = pack2(b1.z * ib_, b1.w * ib_);
    *(uint4*)(nb_bf + (size_t)row * DD + 8 * lane) = o;
}

// ---------------------------------------------------------------------------
// K2: naT_bf[b][e][s] = bf16( a[b][s][e] * inv_a[b][s] )  (LDS transpose)
// grid: (D/64, T/64, B), 256 thr
// ---------------------------------------------------------------------------
__global__ __launch_bounds__(256)
void k_mk_naT(const float* __restrict__ a, const float* __restrict__ inv_a,
              unsigned short* __restrict__ naT) {
    const int bz = blockIdx.z;
    const int e0 = blockIdx.x * 64;
    const int s0 = blockIdx.y * 64;
    __shared__ float Ts[64][65];
    const int tid = threadIdx.x;
    const float* ab = a + (size_t)bz * TT * DD;
#pragma unroll
    for (int i = 0; i < 4; ++i) {
        const int sr = (tid >> 4) + i * 16;
        const int ec = (tid & 15) * 4;
        float4 v = *(const float4*)(ab + (size_t)(s0 + sr) * DD + e0 + ec);
        const float s = inv_a[bz * TT + s0 + sr];
        Ts[sr][ec + 0] = v.x * s; Ts[sr][ec + 1] = v.y * s;
        Ts[sr][ec + 2] = v.z * s; Ts[sr][ec + 3] = v.w * s;
    }
    __syncthreads();
    unsigned short* nb = naT + (size_t)bz * DD * TT;
#pragma unroll
    for (int i = 0; i < 2; ++i) {
        const int el = (tid >> 3) + i * 32;
        const int s8 = (tid & 7) * 8;
        uint4 o;
        o.x = pack2(Ts[s8 + 0][el], Ts[s8 + 1][el]);
        o.y = pack2(Ts[s8 + 2][el], Ts[s8 + 3][el]);
        o.z = pack2(Ts[s8 + 4][el], Ts[s8 + 5][el]);
        o.w = pack2(Ts[s8 + 6][el], Ts[s8 + 7][el]);
        *(uint4*)(nb + (size_t)(e0 + el) * TT + s0 + s8) = o;
    }
}

// ---------------------------------------------------------------------------
// K3: G_bf[b][t][s] = bf16( sum_d nb[t,d]*nb[s,d] )  from nb_bf (pure copies)
// MFMA bf16 16x16x32, 64x64 tile, 4 waves (2x2 of 32x32), BK=32.
// grid: (T/64, T/64, B), 256 thr
// ---------------------------------------------------------------------------
__global__ __launch_bounds__(256)
void k_gemm_g(const unsigned short* __restrict__ nb,
              unsigned short* __restrict__ G) {
    const int bz = blockIdx.z;
    const int t0 = blockIdx.y * 64;
    const int s0 = blockIdx.x * 64;
    __shared__ __align__(16) unsigned short As[64 * 40];
    __shared__ __align__(16) unsigned short Bs[64 * 40];

    const int tid  = threadIdx.x;
    const int wave = tid >> 6, lane = tid & 63;
    const int quad = lane >> 4, ln = lane & 15;
    const int wm = wave >> 1, wn = wave & 1;

    const unsigned short* nbb = nb + (size_t)bz * TT * DD;

    const int lr = tid >> 2;          // 0..63
    const int c8 = (tid & 3) * 8;     // 0..24

    f32x4 acc[2][2];
#pragma unroll
    for (int i = 0; i < 2; ++i)
#pragma unroll
        for (int j = 0; j < 2; ++j)
#pragma unroll
            for (int r = 0; r < 4; ++r) acc[i][j][r] = 0.f;

    for (int k0 = 0; k0 < DD; k0 += 32) {
        *(uint4*)&As[lr * 40 + c8] =
            *(const uint4*)(nbb + (size_t)(t0 + lr) * DD + k0 + c8);
        *(uint4*)&Bs[lr * 40 + c8] =
            *(const uint4*)(nbb + (size_t)(s0 + lr) * DD + k0 + c8);
        __syncthreads();
        short8 af[2], bf[2];
        af[0] = *(const short8*)&As[(wm * 32 + ln) * 40 + quad * 8];
        af[1] = *(const short8*)&As[(wm * 32 + 16 + ln) * 40 + quad * 8];
        bf[0] = *(const short8*)&Bs[(wn * 32 + ln) * 40 + quad * 8];
        bf[1] = *(const short8*)&Bs[(wn * 32 + 16 + ln) * 40 + quad * 8];
#pragma unroll
        for (int i = 0; i < 2; ++i)
#pragma unroll
            for (int j = 0; j < 2; ++j)
                acc[i][j] = __builtin_amdgcn_mfma_f32_16x16x32_bf16(
                    af[i], bf[j], acc[i][j], 0, 0, 0);
        __syncthreads();
    }
    unsigned short* Gb = G + (size_t)bz * TT * TT;
#pragma unroll
    for (int i = 0; i < 2; ++i)
#pragma unroll
        for (int j = 0; j < 2; ++j) {
            const int col = s0 + wn * 32 + j * 16 + ln;
#pragma unroll
            for (int r = 0; r < 4; ++r) {
                const int row = t0 + wm * 32 + i * 16 + quad * 4 + r;
                Gb[(size_t)row * TT + col] = f2bf(acc[i][j][r]);
            }
        }
}

// ---------------------------------------------------------------------------
// K4: H[b][t][e] = sum_s G[t,s] * na[s,e]  (A=G_bf, B=naT_bf, both K-contig)
//     H stored bf16; fused epilogue q[b][e] += sum_t na[t,e]*H[t,e] (atomics,
//     fp32 accumulate).  grid: (D/64, T/64, B), 256 thr
// ---------------------------------------------------------------------------
__global__ __launch_bounds__(256)
void k_gemm_h(const unsigned short* __restrict__ G,
              const unsigned short* __restrict__ naT,
              const float* __restrict__ a, const float* __restrict__ inv_a,
              unsigned short* __restrict__ H, float* __restrict__ q) {
    const int bz = blockIdx.z;
    const int t0 = blockIdx.y * 64;
    const int e0 = blockIdx.x * 64;
    __shared__ __align__(16) unsigned short As[64 * 40];
    __shared__ __align__(16) unsigned short Bs[64 * 40];
    __shared__ float qsum[64];

    const int tid  = threadIdx.x;
    const int wave = tid >> 6, lane = tid & 63;
    const int quad = lane >> 4, ln = lane & 15;
    const int wm = wave >> 1, wn = wave & 1;

    const unsigned short* Gb = G + (size_t)bz * TT * TT;
    const unsigned short* Nb = naT + (size_t)bz * DD * TT;

    const int lr = tid >> 2;          // 0..63
    const int c8 = (tid & 3) * 8;     // 0..24

    f32x4 acc[2][2];
#pragma unroll
    for (int i = 0; i < 2; ++i)
#pragma unroll
        for (int j = 0; j < 2; ++j)
#pragma unroll
            for (int r = 0; r < 4; ++r) acc[i][j][r] = 0.f;

    for (int k0 = 0; k0 < TT; k0 += 32) {
        *(uint4*)&As[lr * 40 + c8] =
            *(const uint4*)(Gb + (size_t)(t0 + lr) * TT + k0 + c8);
        *(uint4*)&Bs[lr * 40 + c8] =
            *(const uint4*)(Nb + (size_t)(e0 + lr) * TT + k0 + c8);
        __syncthreads();
        short8 af[2], bf[2];
        af[0] = *(const short8*)&As[(wm * 32 + ln) * 40 + quad * 8];
        af[1] = *(const short8*)&As[(wm * 32 + 16 + ln) * 40 + quad * 8];
        bf[0] = *(const short8*)&Bs[(wn * 32 + ln) * 40 + quad * 8];
        bf[1] = *(const short8*)&Bs[(wn * 32 + 16 + ln) * 40 + quad * 8];
#pragma unroll
        for (int i = 0; i < 2; ++i)
#pragma unroll
            for (int j = 0; j < 2; ++j)
                acc[i][j] = __builtin_amdgcn_mfma_f32_16x16x32_bf16(
                    af[i], bf[j], acc[i][j], 0, 0, 0);
        __syncthreads();
    }

    if (tid < 64) qsum[tid] = 0.f;
    __syncthreads();

    const float* ab = a + (size_t)bz * TT * DD;
    const float* ia = inv_a + bz * TT;
    unsigned short* Hb = H + (size_t)bz * TT * DD;
#pragma unroll
    for (int j = 0; j < 2; ++j) {
        const int col = e0 + wn * 32 + j * 16 + ln;
        float qp = 0.f;
#pragma unroll
        for (int i = 0; i < 2; ++i) {
#pragma unroll
            for (int r = 0; r < 4; ++r) {
                const int row = t0 + wm * 32 + i * 16 + quad * 4 + r;
                const float hv = acc[i][j][r];
                Hb[(size_t)row * DD + col] = f2bf(hv);
                qp = fmaf(ab[(size_t)row * DD + col] * ia[row], hv, qp);
            }
        }
        qp += __shfl_xor(qp, 16);
        qp += __shfl_xor(qp, 32);
        if (quad == 0) atomicAdd(&qsum[wn * 32 + j * 16 + ln], qp);
    }
    __syncthreads();
    if (tid < 64) atomicAdd(q + bz * DD + e0 + tid, qsum[tid]);
}

// ---------------------------------------------------------------------------
// K5: persp with on-the-fly hmean = H_bf * rsqrt(max(q,eps))
// Lane l owns d = 8l .. 8l+7 (matches bf16 H packing).
// ---------------------------------------------------------------------------
__global__ __launch_bounds__(64)
void k_persp(const float* __restrict__ a, const unsigned short* __restrict__ H,
             const float* __restrict__ q, const float* __restrict__ W,
             float* __restrict__ out) {
    const int row  = blockIdx.x;        // b*T + t
    const int b    = row >> 8;
    const int lane = threadIdx.x;
    const float4* pa = (const float4*)(a + (size_t)row * DD);
    const float4* pq = (const float4*)(q + (size_t)b * DD);
    float4 a0 = pa[2 * lane], a1 = pa[2 * lane + 1];
    float4 q0 = pq[2 * lane], q1 = pq[2 * lane + 1];
    uint4 hu = *(const uint4*)(H + (size_t)row * DD + 8 * lane);
    const float av[8] = {a0.x, a0.y, a0.z, a0.w, a1.x, a1.y, a1.z, a1.w};
    const float qv[8] = {q0.x, q0.y, q0.z, q0.w, q1.x, q1.y, q1.z, q1.w};
    float hv[8] = {bf2f(hu.x & 0xffffu), bf2f(hu.x >> 16),
                   bf2f(hu.y & 0xffffu), bf2f(hu.y >> 16),
                   bf2f(hu.z & 0xffffu), bf2f(hu.z >> 16),
                   bf2f(hu.w & 0xffffu), bf2f(hu.w >> 16)};
    float ah[8], aa[8], hh[8];
#pragma unroll
    for (int t = 0; t < 8; ++t) {
        hv[t] *= rsqrtf(fmaxf(qv[t], EPSF));
        ah[t] = av[t] * hv[t];
        aa[t] = av[t] * av[t];
        hh[t] = hv[t] * hv[t];
    }
    for (int p = 0; p < PP; ++p) {
        const float4* pw = (const float4*)(W + (size_t)p * DD);
        float4 w0 = pw[2 * lane], w1 = pw[2 * lane + 1];
        const float wv[8] = {w0.x, w0.y, w0.z, w0.w, w1.x, w1.y, w1.z, w1.w};
        float s1 = 0.f, s2 = 0.f, s3 = 0.f;
#pragma unroll
        for (int t = 0; t < 8; ++t) {
            const float ww = wv[t] * wv[t];
            s1 = fmaf(ah[t], ww, s1);
            s2 = fmaf(aa[t], ww, s2);
            s3 = fmaf(hh[t], ww, s3);
        }
#pragma unroll
        for (int off = 1; off < 64; off <<= 1) {
            s1 += __shfl_xor(s1, off);
            s2 += __shfl_xor(s2, off);
            s3 += __shfl_xor(s3, off);
        }
        if (lane == 0) {
            const float v = s1 * rsqrtf(fmaxf(s2, EPSF)) * rsqrtf(fmaxf(s3, EPSF));
            out[(size_t)row * PP + p] = v;
            out[(size_t)BTP + (size_t)row * PP + p] = v;
        }
    }
}

// ---------------------------------------------------------------------------
extern "C" void kernel_launch(void* const* d_in, const int* in_sizes, int n_in,
                              void* d_out, int out_size, void* d_ws, size_t ws_size,
                              hipStream_t stream) {
    (void)in_sizes; (void)n_in; (void)out_size; (void)ws_size;
    const float* a = (const float*)d_in[0];   // (B,T,D)
    const float* b = (const float*)d_in[1];   // (B,T,D)
    const float* W = (const float*)d_in[2];   // (P,D)
    float* out = (float*)d_out;

    char* ws = (char*)d_ws;
    unsigned short* nb_bf = (unsigned short*)ws;                       // 8 MB
    unsigned short* naT   = (unsigned short*)(ws + (8u << 20));        // 8 MB
    unsigned short* G_bf  = (unsigned short*)(ws + (16u << 20));       // 4 MB
    unsigned short* H_bf  = (unsigned short*)(ws + (20u << 20));       // 8 MB
    float* q    = (float*)(ws + (28u << 20));                          // 64 KB
    float* inv_a = (float*)(ws + (28u << 20) + (64u << 10));
    float* inv_b = inv_a + BB * TT;

    hipMemsetAsync(q, 0, (size_t)BB * DD * sizeof(float), stream);

    k_prep<<<BB * TT, 64, 0, stream>>>(a, b, inv_a, inv_b, nb_bf);

    dim3 gT(DD / 64, TT / 64, BB);
    k_mk_naT<<<gT, 256, 0, stream>>>(a, inv_a, naT);

    dim3 gG(TT / 64, TT / 64, BB);
    k_gemm_g<<<gG, 256, 0, stream>>>(nb_bf, G_bf);

    dim3 gH(DD / 64, TT / 64, BB);
    k_gemm_h<<<gH, 256, 0, stream>>>(G_bf, naT, a, inv_a, H_bf, q);

    k_persp<<<BB * TT, 64, 0, stream>>>(a, H_bf, q, W, out);
}

// Round 4
// 122.553 us; speedup vs baseline: 2.0333x; 1.2028x over previous
//
#include <hip/hip_runtime.h>

// Problem constants: B=32, T=256, D=512, P=20
#define BB 32
#define TT 256
#define DD 512
#define PP 20
#define EPSF 1e-12f
#define BTP (BB * TT * PP)   // 163840

typedef __attribute__((ext_vector_type(8))) short short8;
typedef __attribute__((ext_vector_type(4))) float f32x4;

__device__ inline unsigned short f2bf(float f) {
    unsigned u = __float_as_uint(f);
    u += 0x7fffu + ((u >> 16) & 1u);          // round-to-nearest-even
    return (unsigned short)(u >> 16);
}
__device__ inline unsigned pack2(float lo, float hi) {
    return (unsigned)f2bf(lo) | ((unsigned)f2bf(hi) << 16);
}
__device__ inline float bf2f(unsigned s) {    // s = 16-bit bf16 payload
    return __uint_as_float(s << 16);
}

union U8 { short8 s; uint4 u; };

// ---------------------------------------------------------------------------
// K1: per-row inverse L2 norms; emit nb_bf = bf16(b*inv_b) and
// na_bf = bf16(a*inv_a), both row-major.  grid = B*T, 64 thr.
// Lane l owns d = 8l .. 8l+7.
// ---------------------------------------------------------------------------
__global__ __launch_bounds__(64)
void k_prep(const float* __restrict__ a, const float* __restrict__ b,
            float* __restrict__ inv_a,
            unsigned short* __restrict__ na_bf,
            unsigned short* __restrict__ nb_bf) {
    const int row  = blockIdx.x;
    const int lane = threadIdx.x;
    const float4* pa = (const float4*)(a + (size_t)row * DD);
    const float4* pb = (const float4*)(b + (size_t)row * DD);
    float4 a0 = pa[2 * lane], a1 = pa[2 * lane + 1];
    float4 b0 = pb[2 * lane], b1 = pb[2 * lane + 1];
    float sa = a0.x * a0.x + a0.y * a0.y + a0.z * a0.z + a0.w * a0.w
             + a1.x * a1.x + a1.y * a1.y + a1.z * a1.z + a1.w * a1.w;
    float sb = b0.x * b0.x + b0.y * b0.y + b0.z * b0.z + b0.w * b0.w
             + b1.x * b1.x + b1.y * b1.y + b1.z * b1.z + b1.w * b1.w;
#pragma unroll
    for (int off = 1; off < 64; off <<= 1) {
        sa += __shfl_xor(sa, off);
        sb += __shfl_xor(sb, off);
    }
    const float ia_ = rsqrtf(fmaxf(sa, EPSF));
    const float ib_ = rsqrtf(fmaxf(sb, EPSF));
    if (lane == 0) inv_a[row] = ia_;
    uint4 oa, ob;
    oa.x = pack2(a0.x * ia_, a0.y * ia_);
    oa.y = pack2(a0.z * ia_, a0.w * ia_);
    oa.z = pack2(a1.x * ia_, a1.y * ia_);
    oa.w = pack2(a1.z * ia_, a1.w * ia_);
    ob.x = pack2(b0.x * ib_, b0.y * ib_);
    ob.y = pack2(b0.z * ib_, b0.w * ib_);
    ob.z = pack2(b1.x * ib_, b1.y * ib_);
    ob.w = pack2(b1.z * ib_, b1.w * ib_);
    *(uint4*)(na_bf + (size_t)row * DD + 8 * lane) = oa;
    *(uint4*)(nb_bf + (size_t)row * DD + 8 * lane) = ob;
}

// ---------------------------------------------------------------------------
// K2: naT_bf[b][e][s] = bf16( a[b][s][e] * inv_a[b][s] )  (LDS transpose)
// grid: (D/64, T/64, B), 256 thr
// ---------------------------------------------------------------------------
__global__ __launch_bounds__(256)
void k_mk_naT(const float* __restrict__ a, const float* __restrict__ inv_a,
              unsigned short* __restrict__ naT) {
    const int bz = blockIdx.z;
    const int e0 = blockIdx.x * 64;
    const int s0 = blockIdx.y * 64;
    __shared__ float Ts[64][65];
    const int tid = threadIdx.x;
    const float* ab = a + (size_t)bz * TT * DD;
#pragma unroll
    for (int i = 0; i < 4; ++i) {
        const int sr = (tid >> 4) + i * 16;
        const int ec = (tid & 15) * 4;
        float4 v = *(const float4*)(ab + (size_t)(s0 + sr) * DD + e0 + ec);
        const float s = inv_a[bz * TT + s0 + sr];
        Ts[sr][ec + 0] = v.x * s; Ts[sr][ec + 1] = v.y * s;
        Ts[sr][ec + 2] = v.z * s; Ts[sr][ec + 3] = v.w * s;
    }
    __syncthreads();
    unsigned short* nb = naT + (size_t)bz * DD * TT;
#pragma unroll
    for (int i = 0; i < 2; ++i) {
        const int el = (tid >> 3) + i * 32;
        const int s8 = (tid & 7) * 8;
        uint4 o;
        o.x = pack2(Ts[s8 + 0][el], Ts[s8 + 1][el]);
        o.y = pack2(Ts[s8 + 2][el], Ts[s8 + 3][el]);
        o.z = pack2(Ts[s8 + 4][el], Ts[s8 + 5][el]);
        o.w = pack2(Ts[s8 + 6][el], Ts[s8 + 7][el]);
        *(uint4*)(nb + (size_t)(e0 + el) * TT + s0 + s8) = o;
    }
}

// ---------------------------------------------------------------------------
// K3: G_bf[b][t][s] = bf16( sum_d nb[t,d]*nb[s,d] )  from nb_bf (pure copies)
// MFMA bf16 16x16x32, 64x64 tile, 4 waves (2x2 of 32x32), BK=32.
// grid: (T/64, T/64, B), 256 thr
// ---------------------------------------------------------------------------
__global__ __launch_bounds__(256)
void k_gemm_g(const unsigned short* __restrict__ nb,
              unsigned short* __restrict__ G) {
    const int bz = blockIdx.z;
    const int t0 = blockIdx.y * 64;
    const int s0 = blockIdx.x * 64;
    __shared__ __align__(16) unsigned short As[64 * 40];
    __shared__ __align__(16) unsigned short Bs[64 * 40];

    const int tid  = threadIdx.x;
    const int wave = tid >> 6, lane = tid & 63;
    const int quad = lane >> 4, ln = lane & 15;
    const int wm = wave >> 1, wn = wave & 1;

    const unsigned short* nbb = nb + (size_t)bz * TT * DD;

    const int lr = tid >> 2;          // 0..63
    const int c8 = (tid & 3) * 8;     // 0..24

    f32x4 acc[2][2];
#pragma unroll
    for (int i = 0; i < 2; ++i)
#pragma unroll
        for (int j = 0; j < 2; ++j)
#pragma unroll
            for (int r = 0; r < 4; ++r) acc[i][j][r] = 0.f;

    for (int k0 = 0; k0 < DD; k0 += 32) {
        *(uint4*)&As[lr * 40 + c8] =
            *(const uint4*)(nbb + (size_t)(t0 + lr) * DD + k0 + c8);
        *(uint4*)&Bs[lr * 40 + c8] =
            *(const uint4*)(nbb + (size_t)(s0 + lr) * DD + k0 + c8);
        __syncthreads();
        short8 af[2], bf[2];
        af[0] = *(const short8*)&As[(wm * 32 + ln) * 40 + quad * 8];
        af[1] = *(const short8*)&As[(wm * 32 + 16 + ln) * 40 + quad * 8];
        bf[0] = *(const short8*)&Bs[(wn * 32 + ln) * 40 + quad * 8];
        bf[1] = *(const short8*)&Bs[(wn * 32 + 16 + ln) * 40 + quad * 8];
#pragma unroll
        for (int i = 0; i < 2; ++i)
#pragma unroll
            for (int j = 0; j < 2; ++j)
                acc[i][j] = __builtin_amdgcn_mfma_f32_16x16x32_bf16(
                    af[i], bf[j], acc[i][j], 0, 0, 0);
        __syncthreads();
    }
    unsigned short* Gb = G + (size_t)bz * TT * TT;
#pragma unroll
    for (int i = 0; i < 2; ++i)
#pragma unroll
        for (int j = 0; j < 2; ++j) {
            const int col = s0 + wn * 32 + j * 16 + ln;
#pragma unroll
            for (int r = 0; r < 4; ++r) {
                const int row = t0 + wm * 32 + i * 16 + quad * 4 + r;
                Gb[(size_t)row * TT + col] = f2bf(acc[i][j][r]);
            }
        }
}

// ---------------------------------------------------------------------------
// K4: H[b][t][e] = sum_s G[t,s] * na[s,e]  (A=G_bf, B=naT_bf, both K-contig)
//     H stored bf16; fused epilogue q[b][e] += sum_t na[t,e]*H[t,e] (atomics,
//     fp32 accumulate, na read from na_bf).  grid: (D/64, T/64, B), 256 thr
// ---------------------------------------------------------------------------
__global__ __launch_bounds__(256)
void k_gemm_h(const unsigned short* __restrict__ G,
              const unsigned short* __restrict__ naT,
              const unsigned short* __restrict__ na,
              unsigned short* __restrict__ H, float* __restrict__ q) {
    const int bz = blockIdx.z;
    const int t0 = blockIdx.y * 64;
    const int e0 = blockIdx.x * 64;
    __shared__ __align__(16) unsigned short As[64 * 40];
    __shared__ __align__(16) unsigned short Bs[64 * 40];
    __shared__ float qsum[64];

    const int tid  = threadIdx.x;
    const int wave = tid >> 6, lane = tid & 63;
    const int quad = lane >> 4, ln = lane & 15;
    const int wm = wave >> 1, wn = wave & 1;

    const unsigned short* Gb = G + (size_t)bz * TT * TT;
    const unsigned short* Nb = naT + (size_t)bz * DD * TT;

    const int lr = tid >> 2;          // 0..63
    const int c8 = (tid & 3) * 8;     // 0..24

    f32x4 acc[2][2];
#pragma unroll
    for (int i = 0; i < 2; ++i)
#pragma unroll
        for (int j = 0; j < 2; ++j)
#pragma unroll
            for (int r = 0; r < 4; ++r) acc[i][j][r] = 0.f;

    for (int k0 = 0; k0 < TT; k0 += 32) {
        *(uint4*)&As[lr * 40 + c8] =
            *(const uint4*)(Gb + (size_t)(t0 + lr) * TT + k0 + c8);
        *(uint4*)&Bs[lr * 40 + c8] =
            *(const uint4*)(Nb + (size_t)(e0 + lr) * TT + k0 + c8);
        __syncthreads();
        short8 af[2], bf[2];
        af[0] = *(const short8*)&As[(wm * 32 + ln) * 40 + quad * 8];
        af[1] = *(const short8*)&As[(wm * 32 + 16 + ln) * 40 + quad * 8];
        bf[0] = *(const short8*)&Bs[(wn * 32 + ln) * 40 + quad * 8];
        bf[1] = *(const short8*)&Bs[(wn * 32 + 16 + ln) * 40 + quad * 8];
#pragma unroll
        for (int i = 0; i < 2; ++i)
#pragma unroll
            for (int j = 0; j < 2; ++j)
                acc[i][j] = __builtin_amdgcn_mfma_f32_16x16x32_bf16(
                    af[i], bf[j], acc[i][j], 0, 0, 0);
        __syncthreads();
    }

    if (tid < 64) qsum[tid] = 0.f;
    __syncthreads();

    const unsigned short* nab = na + (size_t)bz * TT * DD;
    unsigned short* Hb = H + (size_t)bz * TT * DD;
#pragma unroll
    for (int j = 0; j < 2; ++j) {
        const int col = e0 + wn * 32 + j * 16 + ln;
        float qp = 0.f;
#pragma unroll
        for (int i = 0; i < 2; ++i) {
#pragma unroll
            for (int r = 0; r < 4; ++r) {
                const int row = t0 + wm * 32 + i * 16 + quad * 4 + r;
                const float hv = acc[i][j][r];
                Hb[(size_t)row * DD + col] = f2bf(hv);
                qp = fmaf(bf2f(nab[(size_t)row * DD + col]), hv, qp);
            }
        }
        qp += __shfl_xor(qp, 16);
        qp += __shfl_xor(qp, 32);
        if (quad == 0) atomicAdd(&qsum[wn * 32 + j * 16 + ln], qp);
    }
    __syncthreads();
    if (tid < 64) atomicAdd(q + bz * DD + e0 + tid, qsum[tid]);
}

// ---------------------------------------------------------------------------
// K5: finalize invq = rsqrt(max(q,eps)) for all B*D=16384 entries AND build
// W2 = bf16(W^2) padded to 32x512 (rows 20..31 zero).  grid: 64 x 256.
// ---------------------------------------------------------------------------
__global__ __launch_bounds__(256)
void k_fin(const float* __restrict__ q, float* __restrict__ invq,
           const float* __restrict__ W, unsigned short* __restrict__ W2) {
    const int i = blockIdx.x * 256 + threadIdx.x;   // 0..16383
    invq[i] = rsqrtf(fmaxf(q[i], EPSF));
    float w = (i < PP * DD) ? W[i] : 0.f;
    W2[i] = f2bf(w * w);
}

// ---------------------------------------------------------------------------
// K6: persp via MFMA.  For a 16-row tile (one wave):
//   s1 = (na*hv) @ W2^T, s2 = na^2 @ W2^T, s3 = hv^2 @ W2^T, hv = H*invq
//   out = s1 * rsqrt(max(s2,eps)) * rsqrt(max(s3,eps))   (scale-invariant in a)
// grid: (T/16, B), 64 thr.  N = 32 (2 tiles of 16; p>=20 discarded).
// ---------------------------------------------------------------------------
__global__ __launch_bounds__(64)
void k_persp_mfma(const unsigned short* __restrict__ na,
                  const unsigned short* __restrict__ H,
                  const float* __restrict__ invq,
                  const unsigned short* __restrict__ W2,
                  float* __restrict__ out) {
    const int b    = blockIdx.y;
    const int r0   = blockIdx.x * 16;
    const int lane = threadIdx.x;
    const int quad = lane >> 4, ln = lane & 15;
    const size_t rowbase = ((size_t)b * TT + r0 + ln) * DD;
    const float* iqb = invq + (size_t)b * DD;

    f32x4 s1[2], s2[2], s3[2];
#pragma unroll
    for (int j = 0; j < 2; ++j)
#pragma unroll
        for (int r = 0; r < 4; ++r) { s1[j][r] = 0.f; s2[j][r] = 0.f; s3[j][r] = 0.f; }

    for (int k0 = 0; k0 < DD; k0 += 32) {
        const int k = k0 + quad * 8;
        uint4 au = *(const uint4*)(na + rowbase + k);
        uint4 hu = *(const uint4*)(H + rowbase + k);
        float4 q0 = *(const float4*)(iqb + k);
        float4 q1 = *(const float4*)(iqb + k + 4);
        const float av[8] = {bf2f(au.x & 0xffffu), bf2f(au.x >> 16),
                             bf2f(au.y & 0xffffu), bf2f(au.y >> 16),
                             bf2f(au.z & 0xffffu), bf2f(au.z >> 16),
                             bf2f(au.w & 0xffffu), bf2f(au.w >> 16)};
        const float qv[8] = {q0.x, q0.y, q0.z, q0.w, q1.x, q1.y, q1.z, q1.w};
        float hv[8] = {bf2f(hu.x & 0xffffu), bf2f(hu.x >> 16),
                       bf2f(hu.y & 0xffffu), bf2f(hu.y >> 16),
                       bf2f(hu.z & 0xffffu), bf2f(hu.z >> 16),
                       bf2f(hu.w & 0xffffu), bf2f(hu.w >> 16)};
#pragma unroll
        for (int t = 0; t < 8; ++t) hv[t] *= qv[t];
        U8 ah, aa, hh;
        ah.u.x = pack2(av[0] * hv[0], av[1] * hv[1]);
        ah.u.y = pack2(av[2] * hv[2], av[3] * hv[3]);
        ah.u.z = pack2(av[4] * hv[4], av[5] * hv[5]);
        ah.u.w = pack2(av[6] * hv[6], av[7] * hv[7]);
        aa.u.x = pack2(av[0] * av[0], av[1] * av[1]);
        aa.u.y = pack2(av[2] * av[2], av[3] * av[3]);
        aa.u.z = pack2(av[4] * av[4], av[5] * av[5]);
        aa.u.w = pack2(av[6] * av[6], av[7] * av[7]);
        hh.u.x = pack2(hv[0] * hv[0], hv[1] * hv[1]);
        hh.u.y = pack2(hv[2] * hv[2], hv[3] * hv[3]);
        hh.u.z = pack2(hv[4] * hv[4], hv[5] * hv[5]);
        hh.u.w = pack2(hv[6] * hv[6], hv[7] * hv[7]);
        short8 bw0 = *(const short8*)(W2 + (size_t)ln * DD + k);
        short8 bw1 = *(const short8*)(W2 + (size_t)(16 + ln) * DD + k);
        s1[0] = __builtin_amdgcn_mfma_f32_16x16x32_bf16(ah.s, bw0, s1[0], 0, 0, 0);
        s1[1] = __builtin_amdgcn_mfma_f32_16x16x32_bf16(ah.s, bw1, s1[1], 0, 0, 0);
        s2[0] = __builtin_amdgcn_mfma_f32_16x16x32_bf16(aa.s, bw0, s2[0], 0, 0, 0);
        s2[1] = __builtin_amdgcn_mfma_f32_16x16x32_bf16(aa.s, bw1, s2[1], 0, 0, 0);
        s3[0] = __builtin_amdgcn_mfma_f32_16x16x32_bf16(hh.s, bw0, s3[0], 0, 0, 0);
        s3[1] = __builtin_amdgcn_mfma_f32_16x16x32_bf16(hh.s, bw1, s3[1], 0, 0, 0);
    }
#pragma unroll
    for (int j = 0; j < 2; ++j) {
        const int p = j * 16 + ln;
        if (p < PP) {
#pragma unroll
            for (int r = 0; r < 4; ++r) {
                const size_t row = (size_t)b * TT + r0 + quad * 4 + r;
                const float v = s1[j][r] * rsqrtf(fmaxf(s2[j][r], EPSF))
                                        * rsqrtf(fmaxf(s3[j][r], EPSF));
                out[row * PP + p] = v;
                out[(size_t)BTP + row * PP + p] = v;
            }
        }
    }
}

// ---------------------------------------------------------------------------
extern "C" void kernel_launch(void* const* d_in, const int* in_sizes, int n_in,
                              void* d_out, int out_size, void* d_ws, size_t ws_size,
                              hipStream_t stream) {
    (void)in_sizes; (void)n_in; (void)out_size; (void)ws_size;
    const float* a = (const float*)d_in[0];   // (B,T,D)
    const float* b = (const float*)d_in[1];   // (B,T,D)
    const float* W = (const float*)d_in[2];   // (P,D)
    float* out = (float*)d_out;

    char* ws = (char*)d_ws;
    unsigned short* nb_bf = (unsigned short*)ws;                       // 8 MB
    unsigned short* naT   = (unsigned short*)(ws + (8u << 20));        // 8 MB
    unsigned short* na_bf = (unsigned short*)(ws + (16u << 20));       // 8 MB
    unsigned short* G_bf  = (unsigned short*)(ws + (24u << 20));       // 4 MB
    unsigned short* H_bf  = (unsigned short*)(ws + (28u << 20));       // 8 MB
    float* q     = (float*)(ws + (36u << 20));                         // 64 KB
    float* invq  = (float*)(ws + (36u << 20) + (64u << 10));           // 64 KB
    unsigned short* W2 = (unsigned short*)(ws + (36u << 20) + (128u << 10)); // 32 KB
    float* inv_a = (float*)(ws + (36u << 20) + (192u << 10));          // 32 KB

    hipMemsetAsync(q, 0, (size_t)BB * DD * sizeof(float), stream);

    k_prep<<<BB * TT, 64, 0, stream>>>(a, b, inv_a, na_bf, nb_bf);

    dim3 gT(DD / 64, TT / 64, BB);
    k_mk_naT<<<gT, 256, 0, stream>>>(a, inv_a, naT);

    dim3 gG(TT / 64, TT / 64, BB);
    k_gemm_g<<<gG, 256, 0, stream>>>(nb_bf, G_bf);

    dim3 gH(DD / 64, TT / 64, BB);
    k_gemm_h<<<gH, 256, 0, stream>>>(G_bf, naT, na_bf, H_bf, q);

    k_fin<<<BB * DD / 256, 256, 0, stream>>>(q, invq, W, W2);

    dim3 gP(TT / 16, BB);
    k_persp_mfma<<<gP, 64, 0, stream>>>(na_bf, H_bf, invq, W2, out);
}

// Round 5
// 118.249 us; speedup vs baseline: 2.1073x; 1.0364x over previous
//
#include <hip/hip_runtime.h>

// Problem constants: B=32, T=256, D=512, P=20
#define BB 32
#define TT 256
#define DD 512
#define PP 20
#define EPSF 1e-12f
#define BTP (BB * TT * PP)   // 163840

typedef __attribute__((ext_vector_type(8))) short short8;
typedef __attribute__((ext_vector_type(4))) float f32x4;

__device__ inline unsigned short f2bf(float f) {
    unsigned u = __float_as_uint(f);
    u += 0x7fffu + ((u >> 16) & 1u);          // round-to-nearest-even
    return (unsigned short)(u >> 16);
}
__device__ inline unsigned pack2(float lo, float hi) {
    return (unsigned)f2bf(lo) | ((unsigned)f2bf(hi) << 16);
}
__device__ inline float bf2f(unsigned s) {    // s = 16-bit bf16 payload
    return __uint_as_float(s << 16);
}

union U8 { short8 s; uint4 u; };

// ---------------------------------------------------------------------------
// K1: per-row inverse L2 norms; emit nb_bf = bf16(b*inv_b) and
// na_bf = bf16(a*inv_a), both row-major.  Also zero q (2 elems/block) and
// build W2 = bf16(W^2) padded to 32x512.  grid = B*T, 64 thr.
// ---------------------------------------------------------------------------
__global__ __launch_bounds__(64)
void k_prep(const float* __restrict__ a, const float* __restrict__ b,
            const float* __restrict__ W,
            unsigned short* __restrict__ na_bf,
            unsigned short* __restrict__ nb_bf,
            float* __restrict__ q, unsigned short* __restrict__ W2) {
    const int row  = blockIdx.x;
    const int lane = threadIdx.x;
    const float4* pa = (const float4*)(a + (size_t)row * DD);
    const float4* pb = (const float4*)(b + (size_t)row * DD);
    float4 a0 = pa[2 * lane], a1 = pa[2 * lane + 1];
    float4 b0 = pb[2 * lane], b1 = pb[2 * lane + 1];
    float sa = a0.x * a0.x + a0.y * a0.y + a0.z * a0.z + a0.w * a0.w
             + a1.x * a1.x + a1.y * a1.y + a1.z * a1.z + a1.w * a1.w;
    float sb = b0.x * b0.x + b0.y * b0.y + b0.z * b0.z + b0.w * b0.w
             + b1.x * b1.x + b1.y * b1.y + b1.z * b1.z + b1.w * b1.w;
#pragma unroll
    for (int off = 1; off < 64; off <<= 1) {
        sa += __shfl_xor(sa, off);
        sb += __shfl_xor(sb, off);
    }
    const float ia_ = rsqrtf(fmaxf(sa, EPSF));
    const float ib_ = rsqrtf(fmaxf(sb, EPSF));
    uint4 oa, ob;
    oa.x = pack2(a0.x * ia_, a0.y * ia_);
    oa.y = pack2(a0.z * ia_, a0.w * ia_);
    oa.z = pack2(a1.x * ia_, a1.y * ia_);
    oa.w = pack2(a1.z * ia_, a1.w * ia_);
    ob.x = pack2(b0.x * ib_, b0.y * ib_);
    ob.y = pack2(b0.z * ib_, b0.w * ib_);
    ob.z = pack2(b1.x * ib_, b1.y * ib_);
    ob.w = pack2(b1.z * ib_, b1.w * ib_);
    *(uint4*)(na_bf + (size_t)row * DD + 8 * lane) = oa;
    *(uint4*)(nb_bf + (size_t)row * DD + 8 * lane) = ob;
    if (lane < 2) {
        const int i2 = 2 * row + lane;       // covers 0 .. 16383 = B*D
        q[i2] = 0.f;
        const float w = (i2 < PP * DD) ? W[i2] : 0.f;
        W2[i2] = f2bf(w * w);
    }
}

// ---------------------------------------------------------------------------
// K2: naT[b][e][s] = na_bf[b][s][e]  (bit-exact bf16 transpose via LDS).
// uint[64][65] tile: odd word stride -> every scalar LDS access is 2-way
// aliasing (free).  grid: (D/64, T/64, B), 256 thr.
// ---------------------------------------------------------------------------
__global__ __launch_bounds__(256)
void k_tr(const unsigned short* __restrict__ na,
          unsigned short* __restrict__ naT) {
    const int bz = blockIdx.z;
    const int e0 = blockIdx.x * 64;
    const int s0 = blockIdx.y * 64;
    __shared__ unsigned int Ts[64][65];
    const int tid = threadIdx.x;
    const unsigned short* nab = na + (size_t)bz * TT * DD;
    unsigned short* naTb = naT + (size_t)bz * DD * TT;
#pragma unroll
    for (int i = 0; i < 2; ++i) {
        const int s  = (tid >> 3) + i * 32;
        const int e8 = (tid & 7) * 8;
        uint4 v = *(const uint4*)(nab + (size_t)(s0 + s) * DD + e0 + e8);
        Ts[s][e8 + 0] = v.x & 0xffffu; Ts[s][e8 + 1] = v.x >> 16;
        Ts[s][e8 + 2] = v.y & 0xffffu; Ts[s][e8 + 3] = v.y >> 16;
        Ts[s][e8 + 4] = v.z & 0xffffu; Ts[s][e8 + 5] = v.z >> 16;
        Ts[s][e8 + 6] = v.w & 0xffffu; Ts[s][e8 + 7] = v.w >> 16;
    }
    __syncthreads();
#pragma unroll
    for (int i = 0; i < 2; ++i) {
        const int el = (tid >> 3) + i * 32;
        const int s8 = (tid & 7) * 8;
        uint4 o;
        o.x = Ts[s8 + 0][el] | (Ts[s8 + 1][el] << 16);
        o.y = Ts[s8 + 2][el] | (Ts[s8 + 3][el] << 16);
        o.z = Ts[s8 + 4][el] | (Ts[s8 + 5][el] << 16);
        o.w = Ts[s8 + 6][el] | (Ts[s8 + 7][el] << 16);
        *(uint4*)(naTb + (size_t)(e0 + el) * TT + s0 + s8) = o;
    }
}

// ---------------------------------------------------------------------------
// K3: G_bf[b][t][s] = bf16( sum_d nb[t,d]*nb[s,d] )  from nb_bf (pure copies)
// MFMA bf16 16x16x32, 64x64 tile, 4 waves (2x2 of 32x32), BK=32.
// grid: (T/64, T/64, B), 256 thr
// ---------------------------------------------------------------------------
__global__ __launch_bounds__(256)
void k_gemm_g(const unsigned short* __restrict__ nb,
              unsigned short* __restrict__ G) {
    const int bz = blockIdx.z;
    const int t0 = blockIdx.y * 64;
    const int s0 = blockIdx.x * 64;
    __shared__ __align__(16) unsigned short As[64 * 40];
    __shared__ __align__(16) unsigned short Bs[64 * 40];

    const int tid  = threadIdx.x;
    const int wave = tid >> 6, lane = tid & 63;
    const int quad = lane >> 4, ln = lane & 15;
    const int wm = wave >> 1, wn = wave & 1;

    const unsigned short* nbb = nb + (size_t)bz * TT * DD;

    const int lr = tid >> 2;          // 0..63
    const int c8 = (tid & 3) * 8;     // 0..24

    f32x4 acc[2][2];
#pragma unroll
    for (int i = 0; i < 2; ++i)
#pragma unroll
        for (int j = 0; j < 2; ++j)
#pragma unroll
            for (int r = 0; r < 4; ++r) acc[i][j][r] = 0.f;

    for (int k0 = 0; k0 < DD; k0 += 32) {
        *(uint4*)&As[lr * 40 + c8] =
            *(const uint4*)(nbb + (size_t)(t0 + lr) * DD + k0 + c8);
        *(uint4*)&Bs[lr * 40 + c8] =
            *(const uint4*)(nbb + (size_t)(s0 + lr) * DD + k0 + c8);
        __syncthreads();
        short8 af[2], bf[2];
        af[0] = *(const short8*)&As[(wm * 32 + ln) * 40 + quad * 8];
        af[1] = *(const short8*)&As[(wm * 32 + 16 + ln) * 40 + quad * 8];
        bf[0] = *(const short8*)&Bs[(wn * 32 + ln) * 40 + quad * 8];
        bf[1] = *(const short8*)&Bs[(wn * 32 + 16 + ln) * 40 + quad * 8];
#pragma unroll
        for (int i = 0; i < 2; ++i)
#pragma unroll
            for (int j = 0; j < 2; ++j)
                acc[i][j] = __builtin_amdgcn_mfma_f32_16x16x32_bf16(
                    af[i], bf[j], acc[i][j], 0, 0, 0);
        __syncthreads();
    }
    unsigned short* Gb = G + (size_t)bz * TT * TT;
#pragma unroll
    for (int i = 0; i < 2; ++i)
#pragma unroll
        for (int j = 0; j < 2; ++j) {
            const int col = s0 + wn * 32 + j * 16 + ln;
#pragma unroll
            for (int r = 0; r < 4; ++r) {
                const int row = t0 + wm * 32 + i * 16 + quad * 4 + r;
                Gb[(size_t)row * TT + col] = f2bf(acc[i][j][r]);
            }
        }
}

// ---------------------------------------------------------------------------
// K4: H[b][t][e] = sum_s G[t,s] * na[s,e]  (A=G_bf, B=naT_bf, both K-contig)
//     H stored bf16; fused epilogue q[b][e] += sum_t na[t,e]*H[t,e] (atomics,
//     fp32 accumulate, na read from na_bf).  grid: (D/64, T/64, B), 256 thr
// ---------------------------------------------------------------------------
__global__ __launch_bounds__(256)
void k_gemm_h(const unsigned short* __restrict__ G,
              const unsigned short* __restrict__ naT,
              const unsigned short* __restrict__ na,
              unsigned short* __restrict__ H, float* __restrict__ q) {
    const int bz = blockIdx.z;
    const int t0 = blockIdx.y * 64;
    const int e0 = blockIdx.x * 64;
    __shared__ __align__(16) unsigned short As[64 * 40];
    __shared__ __align__(16) unsigned short Bs[64 * 40];
    __shared__ float qsum[64];

    const int tid  = threadIdx.x;
    const int wave = tid >> 6, lane = tid & 63;
    const int quad = lane >> 4, ln = lane & 15;
    const int wm = wave >> 1, wn = wave & 1;

    const unsigned short* Gb = G + (size_t)bz * TT * TT;
    const unsigned short* Nb = naT + (size_t)bz * DD * TT;

    const int lr = tid >> 2;          // 0..63
    const int c8 = (tid & 3) * 8;     // 0..24

    f32x4 acc[2][2];
#pragma unroll
    for (int i = 0; i < 2; ++i)
#pragma unroll
        for (int j = 0; j < 2; ++j)
#pragma unroll
            for (int r = 0; r < 4; ++r) acc[i][j][r] = 0.f;

    for (int k0 = 0; k0 < TT; k0 += 32) {
        *(uint4*)&As[lr * 40 + c8] =
            *(const uint4*)(Gb + (size_t)(t0 + lr) * TT + k0 + c8);
        *(uint4*)&Bs[lr * 40 + c8] =
            *(const uint4*)(Nb + (size_t)(e0 + lr) * TT + k0 + c8);
        __syncthreads();
        short8 af[2], bf[2];
        af[0] = *(const short8*)&As[(wm * 32 + ln) * 40 + quad * 8];
        af[1] = *(const short8*)&As[(wm * 32 + 16 + ln) * 40 + quad * 8];
        bf[0] = *(const short8*)&Bs[(wn * 32 + ln) * 40 + quad * 8];
        bf[1] = *(const short8*)&Bs[(wn * 32 + 16 + ln) * 40 + quad * 8];
#pragma unroll
        for (int i = 0; i < 2; ++i)
#pragma unroll
            for (int j = 0; j < 2; ++j)
                acc[i][j] = __builtin_amdgcn_mfma_f32_16x16x32_bf16(
                    af[i], bf[j], acc[i][j], 0, 0, 0);
        __syncthreads();
    }

    if (tid < 64) qsum[tid] = 0.f;
    __syncthreads();

    const unsigned short* nab = na + (size_t)bz * TT * DD;
    unsigned short* Hb = H + (size_t)bz * TT * DD;
#pragma unroll
    for (int j = 0; j < 2; ++j) {
        const int col = e0 + wn * 32 + j * 16 + ln;
        float qp = 0.f;
#pragma unroll
        for (int i = 0; i < 2; ++i) {
#pragma unroll
            for (int r = 0; r < 4; ++r) {
                const int row = t0 + wm * 32 + i * 16 + quad * 4 + r;
                const float hv = acc[i][j][r];
                Hb[(size_t)row * DD + col] = f2bf(hv);
                qp = fmaf(bf2f(nab[(size_t)row * DD + col]), hv, qp);
            }
        }
        qp += __shfl_xor(qp, 16);
        qp += __shfl_xor(qp, 32);
        if (quad == 0) atomicAdd(&qsum[wn * 32 + j * 16 + ln], qp);
    }
    __syncthreads();
    if (tid < 64) atomicAdd(q + bz * DD + e0 + tid, qsum[tid]);
}

// ---------------------------------------------------------------------------
// K5: persp via MFMA.  invq computed in-kernel from q into LDS.
//   s1 = (na*hv) @ W2^T, s2 = na^2 @ W2^T, s3 = hv^2 @ W2^T, hv = H*invq
//   out = s1 * rsqrt(max(s2,eps)) * rsqrt(max(s3,eps))
// grid: (T/16, B), 64 thr.  N = 32 (2 tiles of 16; p>=20 discarded).
// ---------------------------------------------------------------------------
__global__ __launch_bounds__(64)
void k_persp_mfma(const unsigned short* __restrict__ na,
                  const unsigned short* __restrict__ H,
                  const float* __restrict__ q,
                  const unsigned short* __restrict__ W2,
                  float* __restrict__ out) {
    const int b    = blockIdx.y;
    const int r0   = blockIdx.x * 16;
    const int lane = threadIdx.x;
    const int quad = lane >> 4, ln = lane & 15;
    const size_t rowbase = ((size_t)b * TT + r0 + ln) * DD;

    __shared__ float qs[DD];
    {
        const float* qb = q + (size_t)b * DD;
        float4 v0 = *(const float4*)(qb + 8 * lane);
        float4 v1 = *(const float4*)(qb + 8 * lane + 4);
        qs[8 * lane + 0] = rsqrtf(fmaxf(v0.x, EPSF));
        qs[8 * lane + 1] = rsqrtf(fmaxf(v0.y, EPSF));
        qs[8 * lane + 2] = rsqrtf(fmaxf(v0.z, EPSF));
        qs[8 * lane + 3] = rsqrtf(fmaxf(v0.w, EPSF));
        qs[8 * lane + 4] = rsqrtf(fmaxf(v1.x, EPSF));
        qs[8 * lane + 5] = rsqrtf(fmaxf(v1.y, EPSF));
        qs[8 * lane + 6] = rsqrtf(fmaxf(v1.z, EPSF));
        qs[8 * lane + 7] = rsqrtf(fmaxf(v1.w, EPSF));
    }
    __syncthreads();

    f32x4 s1[2], s2[2], s3[2];
#pragma unroll
    for (int j = 0; j < 2; ++j)
#pragma unroll
        for (int r = 0; r < 4; ++r) { s1[j][r] = 0.f; s2[j][r] = 0.f; s3[j][r] = 0.f; }

    for (int k0 = 0; k0 < DD; k0 += 32) {
        const int k = k0 + quad * 8;
        uint4 au = *(const uint4*)(na + rowbase + k);
        uint4 hu = *(const uint4*)(H + rowbase + k);
        float4 q0 = *(const float4*)&qs[k];
        float4 q1 = *(const float4*)&qs[k + 4];
        const float av[8] = {bf2f(au.x & 0xffffu), bf2f(au.x >> 16),
                             bf2f(au.y & 0xffffu), bf2f(au.y >> 16),
                             bf2f(au.z & 0xffffu), bf2f(au.z >> 16),
                             bf2f(au.w & 0xffffu), bf2f(au.w >> 16)};
        const float qv[8] = {q0.x, q0.y, q0.z, q0.w, q1.x, q1.y, q1.z, q1.w};
        float hv[8] = {bf2f(hu.x & 0xffffu), bf2f(hu.x >> 16),
                       bf2f(hu.y & 0xffffu), bf2f(hu.y >> 16),
                       bf2f(hu.z & 0xffffu), bf2f(hu.z >> 16),
                       bf2f(hu.w & 0xffffu), bf2f(hu.w >> 16)};
#pragma unroll
        for (int t = 0; t < 8; ++t) hv[t] *= qv[t];
        U8 ah, aa, hh;
        ah.u.x = pack2(av[0] * hv[0], av[1] * hv[1]);
        ah.u.y = pack2(av[2] * hv[2], av[3] * hv[3]);
        ah.u.z = pack2(av[4] * hv[4], av[5] * hv[5]);
        ah.u.w = pack2(av[6] * hv[6], av[7] * hv[7]);
        aa.u.x = pack2(av[0] * av[0], av[1] * av[1]);
        aa.u.y = pack2(av[2] * av[2], av[3] * av[3]);
        aa.u.z = pack2(av[4] * av[4], av[5] * av[5]);
        aa.u.w = pack2(av[6] * av[6], av[7] * av[7]);
        hh.u.x = pack2(hv[0] * hv[0], hv[1] * hv[1]);
        hh.u.y = pack2(hv[2] * hv[2], hv[3] * hv[3]);
        hh.u.z = pack2(hv[4] * hv[4], hv[5] * hv[5]);
        hh.u.w = pack2(hv[6] * hv[6], hv[7] * hv[7]);
        short8 bw0 = *(const short8*)(W2 + (size_t)ln * DD + k);
        short8 bw1 = *(const short8*)(W2 + (size_t)(16 + ln) * DD + k);
        s1[0] = __builtin_amdgcn_mfma_f32_16x16x32_bf16(ah.s, bw0, s1[0], 0, 0, 0);
        s1[1] = __builtin_amdgcn_mfma_f32_16x16x32_bf16(ah.s, bw1, s1[1], 0, 0, 0);
        s2[0] = __builtin_amdgcn_mfma_f32_16x16x32_bf16(aa.s, bw0, s2[0], 0, 0, 0);
        s2[1] = __builtin_amdgcn_mfma_f32_16x16x32_bf16(aa.s, bw1, s2[1], 0, 0, 0);
        s3[0] = __builtin_amdgcn_mfma_f32_16x16x32_bf16(hh.s, bw0, s3[0], 0, 0, 0);
        s3[1] = __builtin_amdgcn_mfma_f32_16x16x32_bf16(hh.s, bw1, s3[1], 0, 0, 0);
    }
#pragma unroll
    for (int j = 0; j < 2; ++j) {
        const int p = j * 16 + ln;
        if (p < PP) {
#pragma unroll
            for (int r = 0; r < 4; ++r) {
                const size_t row = (size_t)b * TT + r0 + quad * 4 + r;
                const float v = s1[j][r] * rsqrtf(fmaxf(s2[j][r], EPSF))
                                        * rsqrtf(fmaxf(s3[j][r], EPSF));
                out[row * PP + p] = v;
                out[(size_t)BTP + row * PP + p] = v;
            }
        }
    }
}

// ---------------------------------------------------------------------------
extern "C" void kernel_launch(void* const* d_in, const int* in_sizes, int n_in,
                              void* d_out, int out_size, void* d_ws, size_t ws_size,
                              hipStream_t stream) {
    (void)in_sizes; (void)n_in; (void)out_size; (void)ws_size;
    const float* a = (const float*)d_in[0];   // (B,T,D)
    const float* b = (const float*)d_in[1];   // (B,T,D)
    const float* W = (const float*)d_in[2];   // (P,D)
    float* out = (float*)d_out;

    char* ws = (char*)d_ws;
    unsigned short* nb_bf = (unsigned short*)ws;                       // 8 MB
    unsigned short* naT   = (unsigned short*)(ws + (8u << 20));        // 8 MB
    unsigned short* na_bf = (unsigned short*)(ws + (16u << 20));       // 8 MB
    unsigned short* G_bf  = (unsigned short*)(ws + (24u << 20));       // 4 MB
    unsigned short* H_bf  = (unsigned short*)(ws + (28u << 20));       // 8 MB
    float* q     = (float*)(ws + (36u << 20));                         // 64 KB
    unsigned short* W2 = (unsigned short*)(ws + (36u << 20) + (64u << 10)); // 32 KB

    // K1: norms + na/nb bf16 + q zero + W2 build
    k_prep<<<BB * TT, 64, 0, stream>>>(a, b, W, na_bf, nb_bf, q, W2);

    // K2: bit-exact bf16 transpose na -> naT
    dim3 gT(DD / 64, TT / 64, BB);
    k_tr<<<gT, 256, 0, stream>>>(na_bf, naT);

    // K3: G = nb nb^T
    dim3 gG(TT / 64, TT / 64, BB);
    k_gemm_g<<<gG, 256, 0, stream>>>(nb_bf, G_bf);

    // K4: H = G na, fused q accumulation
    dim3 gH(DD / 64, TT / 64, BB);
    k_gemm_h<<<gH, 256, 0, stream>>>(G_bf, naT, na_bf, H_bf, q);

    // K5: perspective outputs (invq inlined)
    dim3 gP(TT / 16, BB);
    k_persp_mfma<<<gP, 64, 0, stream>>>(na_bf, H_bf, q, W2, out);
}

// Round 6
// 113.859 us; speedup vs baseline: 2.1885x; 1.0386x over previous
//
#include <hip/hip_runtime.h>
#include <hip/hip_bf16.h>

// Problem constants: B=32, T=256, D=512, P=20
#define BB 32
#define TT 256
#define DD 512
#define PP 20
#define EPSF 1e-12f
#define BTP (BB * TT * PP)   // 163840

typedef __attribute__((ext_vector_type(8))) short short8;
typedef __attribute__((ext_vector_type(4))) float f32x4;

__device__ inline unsigned short f2bf(float f) {
    unsigned u = __float_as_uint(f);
    u += 0x7fffu + ((u >> 16) & 1u);          // round-to-nearest-even
    return (unsigned short)(u >> 16);
}
// HW packed f32x2 -> bf16x2 (v_cvt_pk_bf16_f32 on gfx950), RNE — bit-identical
// to f2bf pairs.  lo -> low 16, hi -> high 16.
__device__ inline unsigned pk2(float lo, float hi) {
    __hip_bfloat162 h = __float22bfloat162_rn(float2{lo, hi});
    union { __hip_bfloat162 h; unsigned u; } c;
    c.h = h;
    return c.u;
}
__device__ inline float bf2f(unsigned s) {    // s = 16-bit bf16 payload
    return __uint_as_float(s << 16);
}

union U8 { short8 s; uint4 u; };

// ---------------------------------------------------------------------------
// K1: per-row inverse L2 norms; emit nb_bf = bf16(b*inv_b) and
// na_bf = bf16(a*inv_a), both row-major.  Also zero q (2 elems/block) and
// build W2 = bf16(W^2) padded to 32x512.  grid = B*T, 64 thr.
// ---------------------------------------------------------------------------
__global__ __launch_bounds__(64)
void k_prep(const float* __restrict__ a, const float* __restrict__ b,
            const float* __restrict__ W,
            unsigned short* __restrict__ na_bf,
            unsigned short* __restrict__ nb_bf,
            float* __restrict__ q, unsigned short* __restrict__ W2) {
    const int row  = blockIdx.x;
    const int lane = threadIdx.x;
    const float4* pa = (const float4*)(a + (size_t)row * DD);
    const float4* pb = (const float4*)(b + (size_t)row * DD);
    float4 a0 = pa[2 * lane], a1 = pa[2 * lane + 1];
    float4 b0 = pb[2 * lane], b1 = pb[2 * lane + 1];
    float sa = a0.x * a0.x + a0.y * a0.y + a0.z * a0.z + a0.w * a0.w
             + a1.x * a1.x + a1.y * a1.y + a1.z * a1.z + a1.w * a1.w;
    float sb = b0.x * b0.x + b0.y * b0.y + b0.z * b0.z + b0.w * b0.w
             + b1.x * b1.x + b1.y * b1.y + b1.z * b1.z + b1.w * b1.w;
#pragma unroll
    for (int off = 1; off < 64; off <<= 1) {
        sa += __shfl_xor(sa, off);
        sb += __shfl_xor(sb, off);
    }
    const float ia_ = rsqrtf(fmaxf(sa, EPSF));
    const float ib_ = rsqrtf(fmaxf(sb, EPSF));
    uint4 oa, ob;
    oa.x = pk2(a0.x * ia_, a0.y * ia_);
    oa.y = pk2(a0.z * ia_, a0.w * ia_);
    oa.z = pk2(a1.x * ia_, a1.y * ia_);
    oa.w = pk2(a1.z * ia_, a1.w * ia_);
    ob.x = pk2(b0.x * ib_, b0.y * ib_);
    ob.y = pk2(b0.z * ib_, b0.w * ib_);
    ob.z = pk2(b1.x * ib_, b1.y * ib_);
    ob.w = pk2(b1.z * ib_, b1.w * ib_);
    *(uint4*)(na_bf + (size_t)row * DD + 8 * lane) = oa;
    *(uint4*)(nb_bf + (size_t)row * DD + 8 * lane) = ob;
    if (lane < 2) {
        const int i2 = 2 * row + lane;       // covers 0 .. 16383 = B*D
        q[i2] = 0.f;
        const float w = (i2 < PP * DD) ? W[i2] : 0.f;
        W2[i2] = f2bf(w * w);
    }
}

// ---------------------------------------------------------------------------
// K2 (fused dispatch): blocks with blockIdx.x < 4 run the G GEMM
// (G[b][t][s] = bf16 sum_d nb[t,d] nb[s,d], MFMA 16x16x32, 64x64 tile);
// blocks with blockIdx.x >= 4 run the bit-exact bf16 transpose na -> naT.
// The two halves are independent (both depend only on k_prep) — fusing them
// into one dispatch removes a stream-serialization bubble and overlaps the
// transpose under the GEMM.
// grid: (4+8, 4, 32), 256 thr.
// ---------------------------------------------------------------------------
__global__ __launch_bounds__(256)
void k_g_tr(const unsigned short* __restrict__ nb,
            const unsigned short* __restrict__ na,
            unsigned short* __restrict__ G,
            unsigned short* __restrict__ naT) {
    __shared__ __align__(16) unsigned int smem[64 * 65];   // 16.25 KB, both uses
    const int bz  = blockIdx.z;
    const int tid = threadIdx.x;

    if (blockIdx.x < 4) {
        // ---------------- GEMM G ----------------
        const int t0 = blockIdx.y * 64;
        const int s0 = blockIdx.x * 64;
        unsigned short* As = (unsigned short*)smem;        // 64*40
        unsigned short* Bs = As + 64 * 40;                 // 64*40

        const int wave = tid >> 6, lane = tid & 63;
        const int quad = lane >> 4, ln = lane & 15;
        const int wm = wave >> 1, wn = wave & 1;

        const unsigned short* nbb = nb + (size_t)bz * TT * DD;

        const int lr = tid >> 2;          // 0..63
        const int c8 = (tid & 3) * 8;     // 0..24

        f32x4 acc[2][2];
#pragma unroll
        for (int i = 0; i < 2; ++i)
#pragma unroll
            for (int j = 0; j < 2; ++j)
#pragma unroll
                for (int r = 0; r < 4; ++r) acc[i][j][r] = 0.f;

        for (int k0 = 0; k0 < DD; k0 += 32) {
            *(uint4*)&As[lr * 40 + c8] =
                *(const uint4*)(nbb + (size_t)(t0 + lr) * DD + k0 + c8);
            *(uint4*)&Bs[lr * 40 + c8] =
                *(const uint4*)(nbb + (size_t)(s0 + lr) * DD + k0 + c8);
            __syncthreads();
            short8 af[2], bf[2];
            af[0] = *(const short8*)&As[(wm * 32 + ln) * 40 + quad * 8];
            af[1] = *(const short8*)&As[(wm * 32 + 16 + ln) * 40 + quad * 8];
            bf[0] = *(const short8*)&Bs[(wn * 32 + ln) * 40 + quad * 8];
            bf[1] = *(const short8*)&Bs[(wn * 32 + 16 + ln) * 40 + quad * 8];
#pragma unroll
            for (int i = 0; i < 2; ++i)
#pragma unroll
                for (int j = 0; j < 2; ++j)
                    acc[i][j] = __builtin_amdgcn_mfma_f32_16x16x32_bf16(
                        af[i], bf[j], acc[i][j], 0, 0, 0);
            __syncthreads();
        }
        unsigned short* Gb = G + (size_t)bz * TT * TT;
#pragma unroll
        for (int i = 0; i < 2; ++i)
#pragma unroll
            for (int j = 0; j < 2; ++j) {
                const int col = s0 + wn * 32 + j * 16 + ln;
                const int row0 = t0 + wm * 32 + i * 16 + quad * 4;
#pragma unroll
                for (int r = 0; r < 4; r += 2) {
                    const unsigned pk = pk2(acc[i][j][r], acc[i][j][r + 1]);
                    Gb[(size_t)(row0 + r) * TT + col] = (unsigned short)pk;
                    Gb[(size_t)(row0 + r + 1) * TT + col] = (unsigned short)(pk >> 16);
                }
            }
    } else {
        // ---------------- transpose na -> naT (bit-exact) ----------------
        const int e0 = (blockIdx.x - 4) * 64;
        const int s0 = blockIdx.y * 64;
        unsigned int (*Ts)[65] = (unsigned int (*)[65])smem;
        const unsigned short* nab = na + (size_t)bz * TT * DD;
        unsigned short* naTb = naT + (size_t)bz * DD * TT;
#pragma unroll
        for (int i = 0; i < 2; ++i) {
            const int s  = (tid >> 3) + i * 32;
            const int e8 = (tid & 7) * 8;
            uint4 v = *(const uint4*)(nab + (size_t)(s0 + s) * DD + e0 + e8);
            Ts[s][e8 + 0] = v.x & 0xffffu; Ts[s][e8 + 1] = v.x >> 16;
            Ts[s][e8 + 2] = v.y & 0xffffu; Ts[s][e8 + 3] = v.y >> 16;
            Ts[s][e8 + 4] = v.z & 0xffffu; Ts[s][e8 + 5] = v.z >> 16;
            Ts[s][e8 + 6] = v.w & 0xffffu; Ts[s][e8 + 7] = v.w >> 16;
        }
        __syncthreads();
#pragma unroll
        for (int i = 0; i < 2; ++i) {
            const int el = (tid >> 3) + i * 32;
            const int s8 = (tid & 7) * 8;
            uint4 o;
            o.x = Ts[s8 + 0][el] | (Ts[s8 + 1][el] << 16);
            o.y = Ts[s8 + 2][el] | (Ts[s8 + 3][el] << 16);
            o.z = Ts[s8 + 4][el] | (Ts[s8 + 5][el] << 16);
            o.w = Ts[s8 + 6][el] | (Ts[s8 + 7][el] << 16);
            *(uint4*)(naTb + (size_t)(e0 + el) * TT + s0 + s8) = o;
        }
    }
}

// ---------------------------------------------------------------------------
// K3: H[b][t][e] = sum_s G[t,s] * na[s,e]  (A=G_bf, B=naT_bf, both K-contig)
//     H stored bf16; fused epilogue q[b][e] += sum_t na[t,e]*H[t,e] (atomics,
//     fp32 accumulate, na read from na_bf).  grid: (D/64, T/64, B), 256 thr
// ---------------------------------------------------------------------------
__global__ __launch_bounds__(256)
void k_gemm_h(const unsigned short* __restrict__ G,
              const unsigned short* __restrict__ naT,
              const unsigned short* __restrict__ na,
              unsigned short* __restrict__ H, float* __restrict__ q) {
    const int bz = blockIdx.z;
    const int t0 = blockIdx.y * 64;
    const int e0 = blockIdx.x * 64;
    __shared__ __align__(16) unsigned short As[64 * 40];
    __shared__ __align__(16) unsigned short Bs[64 * 40];
    __shared__ float qsum[64];

    const int tid  = threadIdx.x;
    const int wave = tid >> 6, lane = tid & 63;
    const int quad = lane >> 4, ln = lane & 15;
    const int wm = wave >> 1, wn = wave & 1;

    const unsigned short* Gb = G + (size_t)bz * TT * TT;
    const unsigned short* Nb = naT + (size_t)bz * DD * TT;

    const int lr = tid >> 2;          // 0..63
    const int c8 = (tid & 3) * 8;     // 0..24

    f32x4 acc[2][2];
#pragma unroll
    for (int i = 0; i < 2; ++i)
#pragma unroll
        for (int j = 0; j < 2; ++j)
#pragma unroll
            for (int r = 0; r < 4; ++r) acc[i][j][r] = 0.f;

    for (int k0 = 0; k0 < TT; k0 += 32) {
        *(uint4*)&As[lr * 40 + c8] =
            *(const uint4*)(Gb + (size_t)(t0 + lr) * TT + k0 + c8);
        *(uint4*)&Bs[lr * 40 + c8] =
            *(const uint4*)(Nb + (size_t)(e0 + lr) * TT + k0 + c8);
        __syncthreads();
        short8 af[2], bf[2];
        af[0] = *(const short8*)&As[(wm * 32 + ln) * 40 + quad * 8];
        af[1] = *(const short8*)&As[(wm * 32 + 16 + ln) * 40 + quad * 8];
        bf[0] = *(const short8*)&Bs[(wn * 32 + ln) * 40 + quad * 8];
        bf[1] = *(const short8*)&Bs[(wn * 32 + 16 + ln) * 40 + quad * 8];
#pragma unroll
        for (int i = 0; i < 2; ++i)
#pragma unroll
            for (int j = 0; j < 2; ++j)
                acc[i][j] = __builtin_amdgcn_mfma_f32_16x16x32_bf16(
                    af[i], bf[j], acc[i][j], 0, 0, 0);
        __syncthreads();
    }

    if (tid < 64) qsum[tid] = 0.f;
    __syncthreads();

    const unsigned short* nab = na + (size_t)bz * TT * DD;
    unsigned short* Hb = H + (size_t)bz * TT * DD;
#pragma unroll
    for (int j = 0; j < 2; ++j) {
        const int col = e0 + wn * 32 + j * 16 + ln;
        float qp = 0.f;
#pragma unroll
        for (int i = 0; i < 2; ++i) {
            const int row0 = t0 + wm * 32 + i * 16 + quad * 4;
#pragma unroll
            for (int r = 0; r < 4; r += 2) {
                const float hv0 = acc[i][j][r];
                const float hv1 = acc[i][j][r + 1];
                const unsigned pk = pk2(hv0, hv1);
                Hb[(size_t)(row0 + r) * DD + col] = (unsigned short)pk;
                Hb[(size_t)(row0 + r + 1) * DD + col] = (unsigned short)(pk >> 16);
                qp = fmaf(bf2f(nab[(size_t)(row0 + r) * DD + col]), hv0, qp);
                qp = fmaf(bf2f(nab[(size_t)(row0 + r + 1) * DD + col]), hv1, qp);
            }
        }
        qp += __shfl_xor(qp, 16);
        qp += __shfl_xor(qp, 32);
        if (quad == 0) atomicAdd(&qsum[wn * 32 + j * 16 + ln], qp);
    }
    __syncthreads();
    if (tid < 64) atomicAdd(q + bz * DD + e0 + tid, qsum[tid]);
}

// ---------------------------------------------------------------------------
// K4: persp via MFMA.  invq computed in-kernel from q into LDS.
//   s1 = (na*hv) @ W2^T, s2 = na^2 @ W2^T, s3 = hv^2 @ W2^T, hv = H*invq
//   out = s1 * rsqrt(max(s2,eps)) * rsqrt(max(s3,eps))
// grid: (T/16, B), 64 thr.  N = 32 (2 tiles of 16; p>=20 discarded).
// ---------------------------------------------------------------------------
__global__ __launch_bounds__(64)
void k_persp_mfma(const unsigned short* __restrict__ na,
                  const unsigned short* __restrict__ H,
                  const float* __restrict__ q,
                  const unsigned short* __restrict__ W2,
                  float* __restrict__ out) {
    const int b    = blockIdx.y;
    const int r0   = blockIdx.x * 16;
    const int lane = threadIdx.x;
    const int quad = lane >> 4, ln = lane & 15;
    const size_t rowbase = ((size_t)b * TT + r0 + ln) * DD;

    __shared__ float qs[DD];
    {
        const float* qb = q + (size_t)b * DD;
        float4 v0 = *(const float4*)(qb + 8 * lane);
        float4 v1 = *(const float4*)(qb + 8 * lane + 4);
        qs[8 * lane + 0] = rsqrtf(fmaxf(v0.x, EPSF));
        qs[8 * lane + 1] = rsqrtf(fmaxf(v0.y, EPSF));
        qs[8 * lane + 2] = rsqrtf(fmaxf(v0.z, EPSF));
        qs[8 * lane + 3] = rsqrtf(fmaxf(v0.w, EPSF));
        qs[8 * lane + 4] = rsqrtf(fmaxf(v1.x, EPSF));
        qs[8 * lane + 5] = rsqrtf(fmaxf(v1.y, EPSF));
        qs[8 * lane + 6] = rsqrtf(fmaxf(v1.z, EPSF));
        qs[8 * lane + 7] = rsqrtf(fmaxf(v1.w, EPSF));
    }
    __syncthreads();

    f32x4 s1[2], s2[2], s3[2];
#pragma unroll
    for (int j = 0; j < 2; ++j)
#pragma unroll
        for (int r = 0; r < 4; ++r) { s1[j][r] = 0.f; s2[j][r] = 0.f; s3[j][r] = 0.f; }

    for (int k0 = 0; k0 < DD; k0 += 32) {
        const int k = k0 + quad * 8;
        uint4 au = *(const uint4*)(na + rowbase + k);
        uint4 hu = *(const uint4*)(H + rowbase + k);
        float4 q0 = *(const float4*)&qs[k];
        float4 q1 = *(const float4*)&qs[k + 4];
        const float av[8] = {bf2f(au.x & 0xffffu), bf2f(au.x >> 16),
                             bf2f(au.y & 0xffffu), bf2f(au.y >> 16),
                             bf2f(au.z & 0xffffu), bf2f(au.z >> 16),
                             bf2f(au.w & 0xffffu), bf2f(au.w >> 16)};
        const float qv[8] = {q0.x, q0.y, q0.z, q0.w, q1.x, q1.y, q1.z, q1.w};
        float hv[8] = {bf2f(hu.x & 0xffffu), bf2f(hu.x >> 16),
                       bf2f(hu.y & 0xffffu), bf2f(hu.y >> 16),
                       bf2f(hu.z & 0xffffu), bf2f(hu.z >> 16),
                       bf2f(hu.w & 0xffffu), bf2f(hu.w >> 16)};
#pragma unroll
        for (int t = 0; t < 8; ++t) hv[t] *= qv[t];
        U8 ah, aa, hh;
        ah.u.x = pk2(av[0] * hv[0], av[1] * hv[1]);
        ah.u.y = pk2(av[2] * hv[2], av[3] * hv[3]);
        ah.u.z = pk2(av[4] * hv[4], av[5] * hv[5]);
        ah.u.w = pk2(av[6] * hv[6], av[7] * hv[7]);
        aa.u.x = pk2(av[0] * av[0], av[1] * av[1]);
        aa.u.y = pk2(av[2] * av[2], av[3] * av[3]);
        aa.u.z = pk2(av[4] * av[4], av[5] * av[5]);
        aa.u.w = pk2(av[6] * av[6], av[7] * av[7]);
        hh.u.x = pk2(hv[0] * hv[0], hv[1] * hv[1]);
        hh.u.y = pk2(hv[2] * hv[2], hv[3] * hv[3]);
        hh.u.z = pk2(hv[4] * hv[4], hv[5] * hv[5]);
        hh.u.w = pk2(hv[6] * hv[6], hv[7] * hv[7]);
        short8 bw0 = *(const short8*)(W2 + (size_t)ln * DD + k);
        short8 bw1 = *(const short8*)(W2 + (size_t)(16 + ln) * DD + k);
        s1[0] = __builtin_amdgcn_mfma_f32_16x16x32_bf16(ah.s, bw0, s1[0], 0, 0, 0);
        s1[1] = __builtin_amdgcn_mfma_f32_16x16x32_bf16(ah.s, bw1, s1[1], 0, 0, 0);
        s2[0] = __builtin_amdgcn_mfma_f32_16x16x32_bf16(aa.s, bw0, s2[0], 0, 0, 0);
        s2[1] = __builtin_amdgcn_mfma_f32_16x16x32_bf16(aa.s, bw1, s2[1], 0, 0, 0);
        s3[0] = __builtin_amdgcn_mfma_f32_16x16x32_bf16(hh.s, bw0, s3[0], 0, 0, 0);
        s3[1] = __builtin_amdgcn_mfma_f32_16x16x32_bf16(hh.s, bw1, s3[1], 0, 0, 0);
    }
#pragma unroll
    for (int j = 0; j < 2; ++j) {
        const int p = j * 16 + ln;
        if (p < PP) {
#pragma unroll
            for (int r = 0; r < 4; ++r) {
                const size_t row = (size_t)b * TT + r0 + quad * 4 + r;
                const float v = s1[j][r] * rsqrtf(fmaxf(s2[j][r], EPSF))
                                        * rsqrtf(fmaxf(s3[j][r], EPSF));
                out[row * PP + p] = v;
                out[(size_t)BTP + row * PP + p] = v;
            }
        }
    }
}

// ---------------------------------------------------------------------------
extern "C" void kernel_launch(void* const* d_in, const int* in_sizes, int n_in,
                              void* d_out, int out_size, void* d_ws, size_t ws_size,
                              hipStream_t stream) {
    (void)in_sizes; (void)n_in; (void)out_size; (void)ws_size;
    const float* a = (const float*)d_in[0];   // (B,T,D)
    const float* b = (const float*)d_in[1];   // (B,T,D)
    const float* W = (const float*)d_in[2];   // (P,D)
    float* out = (float*)d_out;

    char* ws = (char*)d_ws;
    unsigned short* nb_bf = (unsigned short*)ws;                       // 8 MB
    unsigned short* naT   = (unsigned short*)(ws + (8u << 20));        // 8 MB
    unsigned short* na_bf = (unsigned short*)(ws + (16u << 20));       // 8 MB
    unsigned short* G_bf  = (unsigned short*)(ws + (24u << 20));       // 4 MB
    unsigned short* H_bf  = (unsigned short*)(ws + (28u << 20));       // 8 MB
    float* q     = (float*)(ws + (36u << 20));                         // 64 KB
    unsigned short* W2 = (unsigned short*)(ws + (36u << 20) + (64u << 10)); // 32 KB

    // L1: norms + na/nb bf16 + q zero + W2 build
    k_prep<<<BB * TT, 64, 0, stream>>>(a, b, W, na_bf, nb_bf, q, W2);

    // L2: fused dispatch — G GEMM (x<4) + na transpose (x>=4)
    dim3 gGT(4 + 8, 4, BB);
    k_g_tr<<<gGT, 256, 0, stream>>>(nb_bf, na_bf, G_bf, naT);

    // L3: H = G na, fused q accumulation
    dim3 gH(DD / 64, TT / 64, BB);
    k_gemm_h<<<gH, 256, 0, stream>>>(G_bf, naT, na_bf, H_bf, q);

    // L4: perspective outputs (invq inlined)
    dim3 gP(TT / 16, BB);
    k_persp_mfma<<<gP, 64, 0, stream>>>(na_bf, H_bf, q, W2, out);
}